// Round 13
// baseline (85.287 us; speedup 1.0000x reference)
//
#include <hip/hip_runtime.h>

#define N_NODES 100000
#define N_EDGES 3200000
#define IN_DIM 192
#define NEG_SLOPE 0.2f

// final bucketing: bin = dst >> 6 (64 nodes/bucket)
#define BSHIFT 6
#define NPB 64
#define N_BUCKETS 1563               // ceil(100000/64)
#define BUCKET_CAP 2560              // mean 2048, sigma~45

// coarse regions: region = dst >> 11 (2048 nodes = 32 bins per region)
#define REG_SHIFT 11
#define NREG 49                      // ceil(100000/2048)
#define REG_BINS 32
#define CAPR 73728                   // per-region intermediate capacity (mean 65.3K)
#define CR_STRIDE 16                 // cursorR padded: one counter per 64B line

#define EPB 8192
#define P1BLK ((N_EDGES + EPB - 1) / EPB)   // 391
#define P2CH 9                               // chunks per region
#define P2BLK (NREG * P2CH)                  // 441
#define PROJ_WPB 16
#define PROJ_BLOCKS ((N_NODES + PROJ_WPB - 1) / PROJ_WPB)
#define AGG_T 512

// ---------------------------------------------------------------------------
// K0: zero the reservation cursors.
// ---------------------------------------------------------------------------
__global__ __launch_bounds__(256) void k0_init(int* __restrict__ cursorR,
                                               int* __restrict__ cursor)
{
    const int i = blockIdx.x * blockDim.x + threadIdx.x;
    if (i < NREG * CR_STRIDE) cursorR[i] = 0;
    if (i < N_BUCKETS) cursor[i] = 0;
}

// ---------------------------------------------------------------------------
// K1 (R11 exact): blocks [0,P1BLK) = pass-1 scatter; rest = projection.
// ---------------------------------------------------------------------------
__global__ __launch_bounds__(1024) void k1_proj_pass1(
    const float* __restrict__ x, const float* __restrict__ W,
    const float* __restrict__ att_src, const float* __restrict__ att_dst,
    float4* __restrict__ node_data, const int* __restrict__ ei,
    unsigned int* __restrict__ ipack, int* __restrict__ cursorR)
{
    __shared__ unsigned int vpack[EPB];       // 32 KB
    __shared__ unsigned char rbin[EPB];       // 8 KB
    __shared__ int hist[NREG], lstart[NREG], cbase[NREG], rankR[NREG];
    const int t = threadIdx.x;

    if (blockIdx.x >= P1BLK) {
        const int wave = (blockIdx.x - P1BLK) * PROJ_WPB + (t >> 6);
        const int lane = t & 63;
        if (wave >= N_NODES) return;
        float p0 = 0.f, p1 = 0.f;
        if (lane < 48) {
            const float4 xv = *reinterpret_cast<const float4*>(x + (size_t)wave * IN_DIM + lane * 4);
            const float* Wr = W + lane * 4 * 2;   // W is [192][2] row-major
            p0 = xv.x * Wr[0] + xv.y * Wr[2] + xv.z * Wr[4] + xv.w * Wr[6];
            p1 = xv.x * Wr[1] + xv.y * Wr[3] + xv.z * Wr[5] + xv.w * Wr[7];
        }
        #pragma unroll
        for (int off = 32; off >= 1; off >>= 1) {
            p0 += __shfl_down(p0, off, 64);
            p1 += __shfl_down(p1, off, 64);
        }
        if (lane == 0) {
            const float as = p0 * att_src[0] + p1 * att_src[1];
            const float ad = p0 * att_dst[0] + p1 * att_dst[1];
            node_data[wave] = make_float4(p0, p1, as, ad);
        }
        return;
    }

    for (int i = t; i < NREG; i += 1024) hist[i] = 0;
    __syncthreads();

    const int e0 = blockIdx.x * EPB;
    const int ecnt = min(EPB, N_EDGES - e0);
    int ss[8], dd[8];
    bool ok[2];
    #pragma unroll
    for (int j = 0; j < 2; ++j) {
        const int e = e0 + (j * 1024 + t) * 4;
        ok[j] = (e < N_EDGES);
        if (ok[j]) {
            const int4 s4 = *reinterpret_cast<const int4*>(ei + e);
            const int4 d4 = *reinterpret_cast<const int4*>(ei + N_EDGES + e);
            ss[j*4+0] = s4.x; ss[j*4+1] = s4.y; ss[j*4+2] = s4.z; ss[j*4+3] = s4.w;
            dd[j*4+0] = d4.x; dd[j*4+1] = d4.y; dd[j*4+2] = d4.z; dd[j*4+3] = d4.w;
            atomicAdd(&hist[d4.x >> REG_SHIFT], 1);
            atomicAdd(&hist[d4.y >> REG_SHIFT], 1);
            atomicAdd(&hist[d4.z >> REG_SHIFT], 1);
            atomicAdd(&hist[d4.w >> REG_SHIFT], 1);
        }
    }
    __syncthreads();

    if (t < 64) {
        const int v = (t < NREG) ? hist[t] : 0;
        int s = v;
        #pragma unroll
        for (int off = 1; off < 64; off <<= 1) {
            const int u = __shfl_up(s, off, 64);
            if (t >= off) s += u;
        }
        if (t < NREG) lstart[t] = s - v;
    }
    __syncthreads();
    if (t < NREG) {
        const int h = hist[t];
        const int rb = (h > 0) ? atomicAdd(&cursorR[t * CR_STRIDE], h) : 0;
        cbase[t] = t * CAPR + rb - lstart[t];
        rankR[t] = 0;
    }
    __syncthreads();

    #pragma unroll
    for (int j = 0; j < 2; ++j) {
        if (ok[j]) {
            #pragma unroll
            for (int k = 0; k < 4; ++k) {
                const int s = ss[j*4+k], d = dd[j*4+k];
                const int r = d >> REG_SHIFT;
                const int rk = atomicAdd(&rankR[r], 1);
                const int p = lstart[r] + rk;
                vpack[p] = ((unsigned int)s & 0xFFFFu) |
                           (((unsigned int)(d & 2047) | (((unsigned int)s >> 16) << 11)) << 16);
                rbin[p] = (unsigned char)r;
            }
        }
    }
    __syncthreads();

    for (int i = t; i < ecnt; i += 1024) {
        const int rb = (int)rbin[i];
        const int addr = cbase[rb] + i;
        if (addr < (rb + 1) * CAPR)
            ipack[addr] = vpack[i];
    }
}

// ---------------------------------------------------------------------------
// K2 (R11 exact): pass-2 into sorted[].
// ---------------------------------------------------------------------------
__global__ __launch_bounds__(1024) void k2_pass2(
    const unsigned int* __restrict__ ipack, const int* __restrict__ cursorR,
    int* __restrict__ cursor, unsigned int* __restrict__ sorted)
{
    __shared__ unsigned int vals[EPB];
    __shared__ unsigned char lbin[EPB];
    __shared__ int hist[REG_BINS], lstart[REG_BINS], cbase[REG_BINS], rankB[REG_BINS];
    const int t = threadIdx.x;
    const int r = blockIdx.x / P2CH, c = blockIdx.x % P2CH;
    const int cnt_r = min(cursorR[r * CR_STRIDE], CAPR);
    const int i0 = c * EPB;
    const int ecnt = min(EPB, cnt_r - i0);
    if (ecnt <= 0) return;

    if (t < REG_BINS) hist[t] = 0;
    __syncthreads();

    unsigned int ent[8];
    int lb[8];
    #pragma unroll
    for (int j = 0; j < 2; ++j) {
        const int base = (j * 1024 + t) * 4;
        uint4 v4 = make_uint4(0, 0, 0, 0);
        if (base < ecnt)
            v4 = *reinterpret_cast<const uint4*>(ipack + (size_t)r * CAPR + i0 + base);
        const unsigned int ev[4] = {v4.x, v4.y, v4.z, v4.w};
        #pragma unroll
        for (int k = 0; k < 4; ++k) {
            const int idx = base + k;
            if (idx < ecnt) {
                const unsigned int e = ev[k];
                const unsigned int hi = e >> 16;
                const int src = (int)(e & 0xFFFFu) | ((int)((hi >> 11) & 1u) << 16);
                const int dstloc = (int)(hi & 2047u);
                lb[j*4+k] = dstloc >> 6;
                ent[j*4+k] = (unsigned int)src | ((unsigned int)(dstloc & 63) << 24);
                atomicAdd(&hist[lb[j*4+k]], 1);
            } else lb[j*4+k] = -1;
        }
    }
    __syncthreads();

    if (t < 64) {
        const int v = (t < REG_BINS) ? hist[t] : 0;
        int s = v;
        #pragma unroll
        for (int off = 1; off < 32; off <<= 1) {
            const int u = __shfl_up(s, off, 64);
            if (t >= off) s += u;
        }
        if (t < REG_BINS) lstart[t] = s - v;
    }
    __syncthreads();
    if (t < REG_BINS) {
        const int gb = r * REG_BINS + t;
        const int h = hist[t];
        const int rb = (h > 0) ? atomicAdd(&cursor[gb], h) : 0;
        cbase[t] = gb * BUCKET_CAP + rb - lstart[t];
        rankB[t] = 0;
    }
    __syncthreads();

    #pragma unroll
    for (int j = 0; j < 8; ++j) {
        if (lb[j] >= 0) {
            const int rk = atomicAdd(&rankB[lb[j]], 1);
            const int p = lstart[lb[j]] + rk;
            vals[p] = ent[j];
            lbin[p] = (unsigned char)lb[j];
        }
    }
    __syncthreads();

    for (int i = t; i < ecnt; i += 1024) {
        const int lb2 = (int)lbin[i];
        const int addr = cbase[lb2] + i;
        if (addr < (r * REG_BINS + lb2 + 1) * BUCKET_CAP)
            sorted[addr] = vals[i];
    }
}

// ---------------------------------------------------------------------------
// K3 (unchanged): aggregate via in-block counting sort -> atomic-free FMA.
// ---------------------------------------------------------------------------
__global__ __launch_bounds__(AGG_T) void f_aggregate_sorted(
    const unsigned int* __restrict__ sorted, const int* __restrict__ cursor,
    const float4* __restrict__ node_data, const float* __restrict__ bias,
    float* __restrict__ out)
{
    __shared__ unsigned int sortedLDS[BUCKET_CAP];
    __shared__ float part0[AGG_T], part1[AGG_T], partw[AGG_T];
    __shared__ int hist[NPB], startB[NPB], rankB[NPB];
    __shared__ float adst[NPB];
    const int b = blockIdx.x, t = threadIdx.x;

    if (t < NPB) {
        const int n = b * NPB + t;
        hist[t] = 0; rankB[t] = 0;
        adst[t] = (n < N_NODES) ? node_data[n].w : 0.f;
    }
    __syncthreads();

    const int cnt = min(cursor[b], BUCKET_CAP);
    const unsigned int* eb = sorted + (size_t)b * BUCKET_CAP;

    unsigned int pk[5];
    #pragma unroll
    for (int j = 0; j < 5; ++j) {
        const int i = t + j * AGG_T;
        pk[j] = (i < cnt) ? eb[i] : 0u;
        if (i < cnt) atomicAdd(&hist[pk[j] >> 24], 1);
    }
    __syncthreads();

    if (t < NPB) {
        const int v = hist[t];
        int s = v;
        #pragma unroll
        for (int off = 1; off < 64; off <<= 1) {
            const int u = __shfl_up(s, off, 64);
            if ((t & 63) >= off) s += u;
        }
        startB[t] = s - v;
    }
    __syncthreads();

    #pragma unroll
    for (int j = 0; j < 5; ++j) {
        const int i = t + j * AGG_T;
        if (i < cnt) {
            const int dl = (int)(pk[j] >> 24);
            const int rk = atomicAdd(&rankB[dl], 1);
            sortedLDS[startB[dl] + rk] = pk[j];
        }
    }
    __syncthreads();

    {
        const int dl = t & 63, sl = t >> 6;
        const float ad = adst[dl];
        const int rs = startB[dl], re = rs + hist[dl];
        float s0 = 0.f, s1 = 0.f, sw = 0.f;
        for (int i = rs + sl; i < re; i += 8) {
            const unsigned int p = sortedLDS[i];
            const int src = (int)(p & 0xFFFFFFu);
            const float4 nd = node_data[src];
            float a = nd.z + ad;
            a = (a >= 0.f) ? a : NEG_SLOPE * a;
            const float w = __expf(a);
            s0 += w * nd.x; s1 += w * nd.y; sw += w;
        }
        part0[t] = s0; part1[t] = s1; partw[t] = sw;
    }
    __syncthreads();

    if (t < NPB) {
        const int n = b * NPB + t;
        if (n < N_NODES) {
            float A0 = 0.f, A1 = 0.f, AW = 0.f;
            #pragma unroll
            for (int k = 0; k < 8; ++k) {
                A0 += part0[t + NPB * k];
                A1 += part1[t + NPB * k];
                AW += partw[t + NPB * k];
            }
            const float4 nd = node_data[n];
            float a = nd.z + nd.w;
            a = (a >= 0.f) ? a : NEG_SLOPE * a;
            const float w = __expf(a);
            const float den = AW + w + 1e-16f;
            const float o0 = (A0 + w * nd.x) / den + bias[0];
            const float o1 = (A1 + w * nd.y) / den + bias[1];
            *reinterpret_cast<float2*>(out + (size_t)n * 2) = make_float2(o0, o1);
        }
    }
}

// ===========================================================================
// DIAGNOSTICS (scratch-only, appended after production path).
// ===========================================================================

// diagA: exact load phase of k1's scatter role (same register stash), then
// XOR-consume. Isolates global-load + any spill cost.
__global__ __launch_bounds__(1024) void diagA_loads(
    const int* __restrict__ ei, unsigned int* __restrict__ scratch)
{
    const int t = threadIdx.x;
    const int e0 = blockIdx.x * EPB;
    int ss[8], dd[8];
    bool ok[2];
    #pragma unroll
    for (int j = 0; j < 2; ++j) {
        const int e = e0 + (j * 1024 + t) * 4;
        ok[j] = (e < N_EDGES);
        if (ok[j]) {
            const int4 s4 = *reinterpret_cast<const int4*>(ei + e);
            const int4 d4 = *reinterpret_cast<const int4*>(ei + N_EDGES + e);
            ss[j*4+0] = s4.x; ss[j*4+1] = s4.y; ss[j*4+2] = s4.z; ss[j*4+3] = s4.w;
            dd[j*4+0] = d4.x; dd[j*4+1] = d4.y; dd[j*4+2] = d4.z; dd[j*4+3] = d4.w;
        } else {
            #pragma unroll
            for (int k = 0; k < 4; ++k) { ss[j*4+k] = 0; dd[j*4+k] = 0; }
        }
    }
    unsigned int acc = 0;
    #pragma unroll
    for (int j = 0; j < 2; ++j) {
        if (ok[j]) {
            #pragma unroll
            for (int k = 0; k < 4; ++k) {
                const int s = ss[j*4+k], d = dd[j*4+k];
                acc ^= ((unsigned int)s & 0xFFFFu) |
                       (((unsigned int)(d & 2047) | (((unsigned int)s >> 16) << 11)) << 16);
                acc += (unsigned int)(d >> REG_SHIFT);
            }
        }
    }
    scratch[(size_t)blockIdx.x * 1024 + t] = acc;
}

// diagC: k1 scatter role MINUS cursor reservation and global writeout.
// loads + hist + scan + rank-place + LDS readback, XOR to scratch.
__global__ __launch_bounds__(1024) void diagC_sort(
    const int* __restrict__ ei, unsigned int* __restrict__ scratch)
{
    __shared__ unsigned int vpack[EPB];
    __shared__ unsigned char rbin[EPB];
    __shared__ int hist[NREG], lstart[NREG], rankR[NREG];
    const int t = threadIdx.x;

    for (int i = t; i < NREG; i += 1024) hist[i] = 0;
    __syncthreads();

    const int e0 = blockIdx.x * EPB;
    const int ecnt = min(EPB, N_EDGES - e0);
    int ss[8], dd[8];
    bool ok[2];
    #pragma unroll
    for (int j = 0; j < 2; ++j) {
        const int e = e0 + (j * 1024 + t) * 4;
        ok[j] = (e < N_EDGES);
        if (ok[j]) {
            const int4 s4 = *reinterpret_cast<const int4*>(ei + e);
            const int4 d4 = *reinterpret_cast<const int4*>(ei + N_EDGES + e);
            ss[j*4+0] = s4.x; ss[j*4+1] = s4.y; ss[j*4+2] = s4.z; ss[j*4+3] = s4.w;
            dd[j*4+0] = d4.x; dd[j*4+1] = d4.y; dd[j*4+2] = d4.z; dd[j*4+3] = d4.w;
            atomicAdd(&hist[d4.x >> REG_SHIFT], 1);
            atomicAdd(&hist[d4.y >> REG_SHIFT], 1);
            atomicAdd(&hist[d4.z >> REG_SHIFT], 1);
            atomicAdd(&hist[d4.w >> REG_SHIFT], 1);
        } else {
            #pragma unroll
            for (int k = 0; k < 4; ++k) { ss[j*4+k] = 0; dd[j*4+k] = 0; }
        }
    }
    __syncthreads();

    if (t < 64) {
        const int v = (t < NREG) ? hist[t] : 0;
        int s = v;
        #pragma unroll
        for (int off = 1; off < 64; off <<= 1) {
            const int u = __shfl_up(s, off, 64);
            if (t >= off) s += u;
        }
        if (t < NREG) lstart[t] = s - v;
    }
    __syncthreads();
    if (t < NREG) rankR[t] = 0;
    __syncthreads();

    #pragma unroll
    for (int j = 0; j < 2; ++j) {
        if (ok[j]) {
            #pragma unroll
            for (int k = 0; k < 4; ++k) {
                const int s = ss[j*4+k], d = dd[j*4+k];
                const int r = d >> REG_SHIFT;
                const int rk = atomicAdd(&rankR[r], 1);
                const int p = lstart[r] + rk;
                vpack[p] = ((unsigned int)s & 0xFFFFu) |
                           (((unsigned int)(d & 2047) | (((unsigned int)s >> 16) << 11)) << 16);
                rbin[p] = (unsigned char)r;
            }
        }
    }
    __syncthreads();

    unsigned int acc = 0;
    for (int i = t; i < ecnt; i += 1024)
        acc ^= vpack[i] + ((unsigned int)rbin[i] << 24);
    scratch[(size_t)blockIdx.x * 1024 + t] = acc;
}

// ------------------- last-resort fallback (round-2 path) -------------------
__global__ __launch_bounds__(256) void proj_kernel(
    const float* __restrict__ x, const float* __restrict__ W,
    const float* __restrict__ att_src, const float* __restrict__ att_dst,
    float4* __restrict__ node_data, float4* __restrict__ accum)
{
    const int wave = (blockIdx.x * blockDim.x + threadIdx.x) >> 6;
    const int lane = threadIdx.x & 63;
    if (wave >= N_NODES) return;
    float p0 = 0.f, p1 = 0.f;
    if (lane < 48) {
        const float4 xv = *reinterpret_cast<const float4*>(x + (size_t)wave * IN_DIM + lane * 4);
        const float* Wr = W + lane * 4 * 2;
        p0 = xv.x * Wr[0] + xv.y * Wr[2] + xv.z * Wr[4] + xv.w * Wr[6];
        p1 = xv.x * Wr[1] + xv.y * Wr[3] + xv.z * Wr[5] + xv.w * Wr[7];
    }
    #pragma unroll
    for (int off = 32; off >= 1; off >>= 1) {
        p0 += __shfl_down(p0, off, 64);
        p1 += __shfl_down(p1, off, 64);
    }
    if (lane == 0) {
        const float as = p0 * att_src[0] + p1 * att_src[1];
        const float ad = p0 * att_dst[0] + p1 * att_dst[1];
        node_data[wave] = make_float4(p0, p1, as, ad);
        if (accum) accum[wave] = make_float4(0.f, 0.f, 0.f, 0.f);
    }
}

__global__ __launch_bounds__(256) void edge_kernel_atomic(
    const int* __restrict__ ei, const float4* __restrict__ node_data,
    float* __restrict__ accum)
{
    const int t = blockIdx.x * blockDim.x + threadIdx.x;
    const int base = t * 4;
    if (base >= N_EDGES) return;
    const int4 s4 = *reinterpret_cast<const int4*>(ei + base);
    const int4 d4 = *reinterpret_cast<const int4*>(ei + N_EDGES + base);
    const int ss[4] = {s4.x, s4.y, s4.z, s4.w};
    const int dd[4] = {d4.x, d4.y, d4.z, d4.w};
    #pragma unroll
    for (int k = 0; k < 4; ++k) {
        const int s = ss[k], d = dd[k];
        const float4 nds = node_data[s];
        const float ad = reinterpret_cast<const float*>(node_data)[d * 4 + 3];
        float a = nds.z + ad;
        a = (a >= 0.f) ? a : NEG_SLOPE * a;
        const float w = __expf(a);
        atomicAdd(&accum[d * 4 + 0], w * nds.x);
        atomicAdd(&accum[d * 4 + 1], w * nds.y);
        atomicAdd(&accum[d * 4 + 2], w);
    }
}

__global__ __launch_bounds__(256) void finalize_kernel(
    const float4* __restrict__ node_data, const float4* __restrict__ accum,
    const float* __restrict__ bias, float* __restrict__ out)
{
    const int n = blockIdx.x * blockDim.x + threadIdx.x;
    if (n >= N_NODES) return;
    const float4 nd = node_data[n];
    const float4 ac = accum[n];
    float a = nd.z + nd.w;
    a = (a >= 0.f) ? a : NEG_SLOPE * a;
    const float w = __expf(a);
    const float den = ac.z + w + 1e-16f;
    const float o0 = (ac.x + w * nd.x) / den + bias[0];
    const float o1 = (ac.y + w * nd.y) / den + bias[1];
    *reinterpret_cast<float2*>(out + (size_t)n * 2) = make_float2(o0, o1);
}

extern "C" void kernel_launch(void* const* d_in, const int* in_sizes, int n_in,
                              void* d_out, int out_size, void* d_ws, size_t ws_size,
                              hipStream_t stream) {
    const float* x       = (const float*)d_in[0];
    const int*   ei      = (const int*)d_in[1];
    const float* W       = (const float*)d_in[3];
    const float* att_src = (const float*)d_in[4];
    const float* att_dst = (const float*)d_in[5];
    const float* bias    = (const float*)d_in[6];
    float* out = (float*)d_out;

    char* p = (char*)d_ws;
    float4* node_data = (float4*)p;            p += (size_t)N_NODES * 16;                 // 1.6 MB
    unsigned int* sorted = (unsigned int*)p;   p += (size_t)N_BUCKETS * BUCKET_CAP * 4;   // 16.0 MB
    unsigned int* ipack  = (unsigned int*)p;   p += (size_t)NREG * CAPR * 4;              // 14.5 MB
    int* cursorR = (int*)p;                    p += (size_t)NREG * CR_STRIDE * 4;
    int* cursor  = (int*)p;                    p += (size_t)N_BUCKETS * 4;
    unsigned int* scratch = (unsigned int*)p;  p += (size_t)P1BLK * 1024 * 4;             // 1.6 MB
    const size_t need = (size_t)(p - (char*)d_ws);

    if (ws_size >= need) {
        // production path (R11 exact)
        k0_init<<<(NREG * CR_STRIDE + N_BUCKETS + 255) / 256, 256, 0, stream>>>(cursorR, cursor);
        k1_proj_pass1<<<P1BLK + PROJ_BLOCKS, 1024, 0, stream>>>(
            x, W, att_src, att_dst, node_data, ei, ipack, cursorR);
        k2_pass2<<<P2BLK, 1024, 0, stream>>>(ipack, cursorR, cursor, sorted);
        f_aggregate_sorted<<<N_BUCKETS, AGG_T, 0, stream>>>(sorted, cursor, node_data, bias, out);
        // diagnostics (scratch only)
        diagA_loads<<<P1BLK, 1024, 0, stream>>>(ei, scratch);
        diagC_sort<<<P1BLK, 1024, 0, stream>>>(ei, scratch);
    } else {
        float4* nd2 = (float4*)d_ws;
        float4* accum = nd2 + N_NODES;
        proj_kernel<<<(N_NODES + 3) / 4, 256, 0, stream>>>(x, W, att_src, att_dst, nd2, accum);
        edge_kernel_atomic<<<(N_EDGES / 4 + 255) / 256, 256, 0, stream>>>(ei, nd2, (float*)accum);
        finalize_kernel<<<(N_NODES + 255) / 256, 256, 0, stream>>>(nd2, accum, bias, out);
    }
}

// Round 14
// 75.350 us; speedup vs baseline: 1.1319x; 1.1319x over previous
//
#include <hip/hip_runtime.h>

#define N_NODES 100000
#define N_EDGES 3200000
#define IN_DIM 192
#define NEG_SLOPE 0.2f

// final bucketing: bin = dst >> 6 (64 nodes/bucket)
#define BSHIFT 6
#define NPB 64
#define N_BUCKETS 1563               // ceil(100000/64)
#define BUCKET_CAP 2560              // mean 2048, sigma~45

// coarse regions: region = dst >> 11 (2048 nodes = 32 bins per region)
#define REG_SHIFT 11
#define NREG 49                      // ceil(100000/2048)
#define REG_BINS 32
#define CAPR 73728                   // per-region intermediate capacity (mean 65.3K)
#define CR_STRIDE 16                 // cursorR padded: one counter per 64B line

#define EPB 8192
#define P1BLK ((N_EDGES + EPB - 1) / EPB)   // 391
#define P2CH 9                               // chunks per region
#define P2BLK (NREG * P2CH)                  // 441
#define AGG_T 512

// ---------------------------------------------------------------------------
// K0: zero the reservation cursors.
// ---------------------------------------------------------------------------
__global__ __launch_bounds__(256) void k0_init(int* __restrict__ cursorR,
                                               int* __restrict__ cursor)
{
    const int i = blockIdx.x * blockDim.x + threadIdx.x;
    if (i < NREG * CR_STRIDE) cursorR[i] = 0;
    if (i < N_BUCKETS) cursor[i] = 0;
}

// ---------------------------------------------------------------------------
// proj_std: standalone projection, one 64-lane wave per node, 256-thr blocks.
// No big LDS allocation -> full occupancy; proven ~13-15 us shape.
// ---------------------------------------------------------------------------
__global__ __launch_bounds__(256) void proj_std(
    const float* __restrict__ x, const float* __restrict__ W,
    const float* __restrict__ att_src, const float* __restrict__ att_dst,
    float4* __restrict__ node_data)
{
    const int wave = (blockIdx.x * blockDim.x + threadIdx.x) >> 6;
    const int lane = threadIdx.x & 63;
    if (wave >= N_NODES) return;
    float p0 = 0.f, p1 = 0.f;
    if (lane < 48) {
        const float4 xv = *reinterpret_cast<const float4*>(x + (size_t)wave * IN_DIM + lane * 4);
        const float* Wr = W + lane * 4 * 2;   // W is [192][2] row-major
        p0 = xv.x * Wr[0] + xv.y * Wr[2] + xv.z * Wr[4] + xv.w * Wr[6];
        p1 = xv.x * Wr[1] + xv.y * Wr[3] + xv.z * Wr[5] + xv.w * Wr[7];
    }
    #pragma unroll
    for (int off = 32; off >= 1; off >>= 1) {
        p0 += __shfl_down(p0, off, 64);
        p1 += __shfl_down(p1, off, 64);
    }
    if (lane == 0) {
        const float as = p0 * att_src[0] + p1 * att_src[1];
        const float ad = p0 * att_dst[0] + p1 * att_dst[1];
        node_data[wave] = make_float4(p0, p1, as, ad);
    }
}

// ---------------------------------------------------------------------------
// K1: pass-1 scatter ONLY (R11 scatter role verbatim; no proj co-residence).
// ipack entry: low16 = src&0xFFFF; high16 = dstloc(11b) | (src>>16)<<11.
// ---------------------------------------------------------------------------
__global__ __launch_bounds__(1024) void k1_pass1(
    const int* __restrict__ ei, unsigned int* __restrict__ ipack,
    int* __restrict__ cursorR)
{
    __shared__ unsigned int vpack[EPB];       // 32 KB
    __shared__ unsigned char rbin[EPB];       // 8 KB
    __shared__ int hist[NREG], lstart[NREG], cbase[NREG], rankR[NREG];
    const int t = threadIdx.x;

    if (t < NREG) hist[t] = 0;
    __syncthreads();

    const int e0 = blockIdx.x * EPB;
    const int ecnt = min(EPB, N_EDGES - e0);
    int ss[8], dd[8];
    bool ok[2];
    #pragma unroll
    for (int j = 0; j < 2; ++j) {
        const int e = e0 + (j * 1024 + t) * 4;
        ok[j] = (e < N_EDGES);
        if (ok[j]) {
            const int4 s4 = *reinterpret_cast<const int4*>(ei + e);
            const int4 d4 = *reinterpret_cast<const int4*>(ei + N_EDGES + e);
            ss[j*4+0] = s4.x; ss[j*4+1] = s4.y; ss[j*4+2] = s4.z; ss[j*4+3] = s4.w;
            dd[j*4+0] = d4.x; dd[j*4+1] = d4.y; dd[j*4+2] = d4.z; dd[j*4+3] = d4.w;
            atomicAdd(&hist[d4.x >> REG_SHIFT], 1);
            atomicAdd(&hist[d4.y >> REG_SHIFT], 1);
            atomicAdd(&hist[d4.z >> REG_SHIFT], 1);
            atomicAdd(&hist[d4.w >> REG_SHIFT], 1);
        }
    }
    __syncthreads();

    if (t < 64) {
        const int v = (t < NREG) ? hist[t] : 0;
        int s = v;
        #pragma unroll
        for (int off = 1; off < 64; off <<= 1) {
            const int u = __shfl_up(s, off, 64);
            if (t >= off) s += u;
        }
        if (t < NREG) lstart[t] = s - v;
    }
    __syncthreads();
    if (t < NREG) {
        const int h = hist[t];
        const int rb = (h > 0) ? atomicAdd(&cursorR[t * CR_STRIDE], h) : 0;
        cbase[t] = t * CAPR + rb - lstart[t];
        rankR[t] = 0;
    }
    __syncthreads();

    #pragma unroll
    for (int j = 0; j < 2; ++j) {
        if (ok[j]) {
            #pragma unroll
            for (int k = 0; k < 4; ++k) {
                const int s = ss[j*4+k], d = dd[j*4+k];
                const int r = d >> REG_SHIFT;
                const int rk = atomicAdd(&rankR[r], 1);
                const int p = lstart[r] + rk;
                vpack[p] = ((unsigned int)s & 0xFFFFu) |
                           (((unsigned int)(d & 2047) | (((unsigned int)s >> 16) << 11)) << 16);
                rbin[p] = (unsigned char)r;
            }
        }
    }
    __syncthreads();

    for (int i = t; i < ecnt; i += 1024) {
        const int rb = (int)rbin[i];
        const int addr = cbase[rb] + i;
        if (addr < (rb + 1) * CAPR)
            ipack[addr] = vpack[i];
    }
}

// ---------------------------------------------------------------------------
// K2 (unchanged): pass-2 into sorted[].
// ---------------------------------------------------------------------------
__global__ __launch_bounds__(1024) void k2_pass2(
    const unsigned int* __restrict__ ipack, const int* __restrict__ cursorR,
    int* __restrict__ cursor, unsigned int* __restrict__ sorted)
{
    __shared__ unsigned int vals[EPB];
    __shared__ unsigned char lbin[EPB];
    __shared__ int hist[REG_BINS], lstart[REG_BINS], cbase[REG_BINS], rankB[REG_BINS];
    const int t = threadIdx.x;
    const int r = blockIdx.x / P2CH, c = blockIdx.x % P2CH;
    const int cnt_r = min(cursorR[r * CR_STRIDE], CAPR);
    const int i0 = c * EPB;
    const int ecnt = min(EPB, cnt_r - i0);
    if (ecnt <= 0) return;

    if (t < REG_BINS) hist[t] = 0;
    __syncthreads();

    unsigned int ent[8];
    int lb[8];
    #pragma unroll
    for (int j = 0; j < 2; ++j) {
        const int base = (j * 1024 + t) * 4;
        uint4 v4 = make_uint4(0, 0, 0, 0);
        if (base < ecnt)
            v4 = *reinterpret_cast<const uint4*>(ipack + (size_t)r * CAPR + i0 + base);
        const unsigned int ev[4] = {v4.x, v4.y, v4.z, v4.w};
        #pragma unroll
        for (int k = 0; k < 4; ++k) {
            const int idx = base + k;
            if (idx < ecnt) {
                const unsigned int e = ev[k];
                const unsigned int hi = e >> 16;
                const int src = (int)(e & 0xFFFFu) | ((int)((hi >> 11) & 1u) << 16);
                const int dstloc = (int)(hi & 2047u);
                lb[j*4+k] = dstloc >> 6;
                ent[j*4+k] = (unsigned int)src | ((unsigned int)(dstloc & 63) << 24);
                atomicAdd(&hist[lb[j*4+k]], 1);
            } else lb[j*4+k] = -1;
        }
    }
    __syncthreads();

    if (t < 64) {
        const int v = (t < REG_BINS) ? hist[t] : 0;
        int s = v;
        #pragma unroll
        for (int off = 1; off < 32; off <<= 1) {
            const int u = __shfl_up(s, off, 64);
            if (t >= off) s += u;
        }
        if (t < REG_BINS) lstart[t] = s - v;
    }
    __syncthreads();
    if (t < REG_BINS) {
        const int gb = r * REG_BINS + t;
        const int h = hist[t];
        const int rb = (h > 0) ? atomicAdd(&cursor[gb], h) : 0;
        cbase[t] = gb * BUCKET_CAP + rb - lstart[t];
        rankB[t] = 0;
    }
    __syncthreads();

    #pragma unroll
    for (int j = 0; j < 8; ++j) {
        if (lb[j] >= 0) {
            const int rk = atomicAdd(&rankB[lb[j]], 1);
            const int p = lstart[lb[j]] + rk;
            vals[p] = ent[j];
            lbin[p] = (unsigned char)lb[j];
        }
    }
    __syncthreads();

    for (int i = t; i < ecnt; i += 1024) {
        const int lb2 = (int)lbin[i];
        const int addr = cbase[lb2] + i;
        if (addr < (r * REG_BINS + lb2 + 1) * BUCKET_CAP)
            sorted[addr] = vals[i];
    }
}

// ---------------------------------------------------------------------------
// K3 (unchanged): aggregate via in-block counting sort -> atomic-free FMA.
// ---------------------------------------------------------------------------
__global__ __launch_bounds__(AGG_T) void f_aggregate_sorted(
    const unsigned int* __restrict__ sorted, const int* __restrict__ cursor,
    const float4* __restrict__ node_data, const float* __restrict__ bias,
    float* __restrict__ out)
{
    __shared__ unsigned int sortedLDS[BUCKET_CAP];
    __shared__ float part0[AGG_T], part1[AGG_T], partw[AGG_T];
    __shared__ int hist[NPB], startB[NPB], rankB[NPB];
    __shared__ float adst[NPB];
    const int b = blockIdx.x, t = threadIdx.x;

    if (t < NPB) {
        const int n = b * NPB + t;
        hist[t] = 0; rankB[t] = 0;
        adst[t] = (n < N_NODES) ? node_data[n].w : 0.f;
    }
    __syncthreads();

    const int cnt = min(cursor[b], BUCKET_CAP);
    const unsigned int* eb = sorted + (size_t)b * BUCKET_CAP;

    unsigned int pk[5];
    #pragma unroll
    for (int j = 0; j < 5; ++j) {
        const int i = t + j * AGG_T;
        pk[j] = (i < cnt) ? eb[i] : 0u;
        if (i < cnt) atomicAdd(&hist[pk[j] >> 24], 1);
    }
    __syncthreads();

    if (t < NPB) {
        const int v = hist[t];
        int s = v;
        #pragma unroll
        for (int off = 1; off < 64; off <<= 1) {
            const int u = __shfl_up(s, off, 64);
            if ((t & 63) >= off) s += u;
        }
        startB[t] = s - v;
    }
    __syncthreads();

    #pragma unroll
    for (int j = 0; j < 5; ++j) {
        const int i = t + j * AGG_T;
        if (i < cnt) {
            const int dl = (int)(pk[j] >> 24);
            const int rk = atomicAdd(&rankB[dl], 1);
            sortedLDS[startB[dl] + rk] = pk[j];
        }
    }
    __syncthreads();

    {
        const int dl = t & 63, sl = t >> 6;
        const float ad = adst[dl];
        const int rs = startB[dl], re = rs + hist[dl];
        float s0 = 0.f, s1 = 0.f, sw = 0.f;
        for (int i = rs + sl; i < re; i += 8) {
            const unsigned int p = sortedLDS[i];
            const int src = (int)(p & 0xFFFFFFu);
            const float4 nd = node_data[src];
            float a = nd.z + ad;
            a = (a >= 0.f) ? a : NEG_SLOPE * a;
            const float w = __expf(a);
            s0 += w * nd.x; s1 += w * nd.y; sw += w;
        }
        part0[t] = s0; part1[t] = s1; partw[t] = sw;
    }
    __syncthreads();

    if (t < NPB) {
        const int n = b * NPB + t;
        if (n < N_NODES) {
            float A0 = 0.f, A1 = 0.f, AW = 0.f;
            #pragma unroll
            for (int k = 0; k < 8; ++k) {
                A0 += part0[t + NPB * k];
                A1 += part1[t + NPB * k];
                AW += partw[t + NPB * k];
            }
            const float4 nd = node_data[n];
            float a = nd.z + nd.w;
            a = (a >= 0.f) ? a : NEG_SLOPE * a;
            const float w = __expf(a);
            const float den = AW + w + 1e-16f;
            const float o0 = (A0 + w * nd.x) / den + bias[0];
            const float o1 = (A1 + w * nd.y) / den + bias[1];
            *reinterpret_cast<float2*>(out + (size_t)n * 2) = make_float2(o0, o1);
        }
    }
}

// ------------------- last-resort fallback (round-2 path) -------------------
__global__ __launch_bounds__(256) void proj_kernel(
    const float* __restrict__ x, const float* __restrict__ W,
    const float* __restrict__ att_src, const float* __restrict__ att_dst,
    float4* __restrict__ node_data, float4* __restrict__ accum)
{
    const int wave = (blockIdx.x * blockDim.x + threadIdx.x) >> 6;
    const int lane = threadIdx.x & 63;
    if (wave >= N_NODES) return;
    float p0 = 0.f, p1 = 0.f;
    if (lane < 48) {
        const float4 xv = *reinterpret_cast<const float4*>(x + (size_t)wave * IN_DIM + lane * 4);
        const float* Wr = W + lane * 4 * 2;
        p0 = xv.x * Wr[0] + xv.y * Wr[2] + xv.z * Wr[4] + xv.w * Wr[6];
        p1 = xv.x * Wr[1] + xv.y * Wr[3] + xv.z * Wr[5] + xv.w * Wr[7];
    }
    #pragma unroll
    for (int off = 32; off >= 1; off >>= 1) {
        p0 += __shfl_down(p0, off, 64);
        p1 += __shfl_down(p1, off, 64);
    }
    if (lane == 0) {
        const float as = p0 * att_src[0] + p1 * att_src[1];
        const float ad = p0 * att_dst[0] + p1 * att_dst[1];
        node_data[wave] = make_float4(p0, p1, as, ad);
        if (accum) accum[wave] = make_float4(0.f, 0.f, 0.f, 0.f);
    }
}

__global__ __launch_bounds__(256) void edge_kernel_atomic(
    const int* __restrict__ ei, const float4* __restrict__ node_data,
    float* __restrict__ accum)
{
    const int t = blockIdx.x * blockDim.x + threadIdx.x;
    const int base = t * 4;
    if (base >= N_EDGES) return;
    const int4 s4 = *reinterpret_cast<const int4*>(ei + base);
    const int4 d4 = *reinterpret_cast<const int4*>(ei + N_EDGES + base);
    const int ss[4] = {s4.x, s4.y, s4.z, s4.w};
    const int dd[4] = {d4.x, d4.y, d4.z, d4.w};
    #pragma unroll
    for (int k = 0; k < 4; ++k) {
        const int s = ss[k], d = dd[k];
        const float4 nds = node_data[s];
        const float ad = reinterpret_cast<const float*>(node_data)[d * 4 + 3];
        float a = nds.z + ad;
        a = (a >= 0.f) ? a : NEG_SLOPE * a;
        const float w = __expf(a);
        atomicAdd(&accum[d * 4 + 0], w * nds.x);
        atomicAdd(&accum[d * 4 + 1], w * nds.y);
        atomicAdd(&accum[d * 4 + 2], w);
    }
}

__global__ __launch_bounds__(256) void finalize_kernel(
    const float4* __restrict__ node_data, const float4* __restrict__ accum,
    const float* __restrict__ bias, float* __restrict__ out)
{
    const int n = blockIdx.x * blockDim.x + threadIdx.x;
    if (n >= N_NODES) return;
    const float4 nd = node_data[n];
    const float4 ac = accum[n];
    float a = nd.z + nd.w;
    a = (a >= 0.f) ? a : NEG_SLOPE * a;
    const float w = __expf(a);
    const float den = ac.z + w + 1e-16f;
    const float o0 = (ac.x + w * nd.x) / den + bias[0];
    const float o1 = (ac.y + w * nd.y) / den + bias[1];
    *reinterpret_cast<float2*>(out + (size_t)n * 2) = make_float2(o0, o1);
}

extern "C" void kernel_launch(void* const* d_in, const int* in_sizes, int n_in,
                              void* d_out, int out_size, void* d_ws, size_t ws_size,
                              hipStream_t stream) {
    const float* x       = (const float*)d_in[0];
    const int*   ei      = (const int*)d_in[1];
    const float* W       = (const float*)d_in[3];
    const float* att_src = (const float*)d_in[4];
    const float* att_dst = (const float*)d_in[5];
    const float* bias    = (const float*)d_in[6];
    float* out = (float*)d_out;

    char* p = (char*)d_ws;
    float4* node_data = (float4*)p;            p += (size_t)N_NODES * 16;                 // 1.6 MB
    unsigned int* sorted = (unsigned int*)p;   p += (size_t)N_BUCKETS * BUCKET_CAP * 4;   // 16.0 MB
    unsigned int* ipack  = (unsigned int*)p;   p += (size_t)NREG * CAPR * 4;              // 14.5 MB
    int* cursorR = (int*)p;                    p += (size_t)NREG * CR_STRIDE * 4;
    int* cursor  = (int*)p;                    p += (size_t)N_BUCKETS * 4;
    const size_t need = (size_t)(p - (char*)d_ws);

    if (ws_size >= need) {
        k0_init<<<(NREG * CR_STRIDE + N_BUCKETS + 255) / 256, 256, 0, stream>>>(cursorR, cursor);
        proj_std<<<(N_NODES + 3) / 4, 256, 0, stream>>>(x, W, att_src, att_dst, node_data);
        k1_pass1<<<P1BLK, 1024, 0, stream>>>(ei, ipack, cursorR);
        k2_pass2<<<P2BLK, 1024, 0, stream>>>(ipack, cursorR, cursor, sorted);
        f_aggregate_sorted<<<N_BUCKETS, AGG_T, 0, stream>>>(sorted, cursor, node_data, bias, out);
    } else {
        float4* nd2 = (float4*)d_ws;
        float4* accum = nd2 + N_NODES;
        proj_kernel<<<(N_NODES + 3) / 4, 256, 0, stream>>>(x, W, att_src, att_dst, nd2, accum);
        edge_kernel_atomic<<<(N_EDGES / 4 + 255) / 256, 256, 0, stream>>>(ei, nd2, (float*)accum);
        finalize_kernel<<<(N_NODES + 255) / 256, 256, 0, stream>>>(nd2, accum, bias, out);
    }
}

// Round 15
// 73.123 us; speedup vs baseline: 1.1664x; 1.0305x over previous
//
#include <hip/hip_runtime.h>

#define N_NODES 100000
#define N_EDGES 3200000
#define IN_DIM 192
#define NEG_SLOPE 0.2f

#define BSHIFT 6
#define NPB 64
#define N_BUCKETS 1563               // ceil(100000/64)
#define BUCKET_CAP 2560              // mult of 4; mean 2048 + pad<=27

#define REG_SHIFT 11
#define NREG 49                      // ceil(100000/2048)
#define REG_BINS 32
#define CAPR 73728                   // mult of 4; mean 65.5K + 5sig + pad<=1.2K
#define CR_STRIDE 16

#define EPB 8192
#define P1BLK ((N_EDGES + EPB - 1) / EPB)   // 391
#define P2CH 9
#define P2BLK (NREG * P2CH)                  // 441
#define PROJ_WPB 16
#define PROJ_BLOCKS ((N_NODES + PROJ_WPB - 1) / PROJ_WPB)
#define AGG_T 512
#define SENT 0xFFFFFFFFu

__global__ __launch_bounds__(256) void k0_init(int* __restrict__ cursorR,
                                               int* __restrict__ cursor)
{
    const int i = blockIdx.x * blockDim.x + threadIdx.x;
    if (i < NREG * CR_STRIDE) cursorR[i] = 0;
    if (i < N_BUCKETS) cursor[i] = 0;
}

// ---------------------------------------------------------------------------
// K1 (fused, R11 structure): blocks [0,P1BLK) = pass-1 region sort with
// PADDED reservations + 16B-aligned uint4 writeout; rest = projection.
// ---------------------------------------------------------------------------
__global__ __launch_bounds__(1024) void k1_proj_pass1(
    const float* __restrict__ x, const float* __restrict__ W,
    const float* __restrict__ att_src, const float* __restrict__ att_dst,
    float4* __restrict__ node_data, const int* __restrict__ ei,
    unsigned int* __restrict__ ipack, int* __restrict__ cursorR)
{
    __shared__ unsigned int vpack[EPB + 4 * NREG];
    __shared__ unsigned char rbin[EPB + 4 * NREG];
    __shared__ int hist[NREG], lstart[NREG], cbase[NREG], rankR[NREG];
    const int t = threadIdx.x;

    if (blockIdx.x >= P1BLK) {
        const int wave = (blockIdx.x - P1BLK) * PROJ_WPB + (t >> 6);
        const int lane = t & 63;
        if (wave >= N_NODES) return;
        float p0 = 0.f, p1 = 0.f;
        if (lane < 48) {
            const float4 xv = *reinterpret_cast<const float4*>(x + (size_t)wave * IN_DIM + lane * 4);
            const float* Wr = W + lane * 4 * 2;   // W is [192][2] row-major
            p0 = xv.x * Wr[0] + xv.y * Wr[2] + xv.z * Wr[4] + xv.w * Wr[6];
            p1 = xv.x * Wr[1] + xv.y * Wr[3] + xv.z * Wr[5] + xv.w * Wr[7];
        }
        #pragma unroll
        for (int off = 32; off >= 1; off >>= 1) {
            p0 += __shfl_down(p0, off, 64);
            p1 += __shfl_down(p1, off, 64);
        }
        if (lane == 0) {
            const float as = p0 * att_src[0] + p1 * att_src[1];
            const float ad = p0 * att_dst[0] + p1 * att_dst[1];
            node_data[wave] = make_float4(p0, p1, as, ad);
        }
        return;
    }

    // ---- scatter role ----
    for (int i = t; i < NREG; i += 1024) hist[i] = 0;
    for (int i = t; i < EPB + 4 * NREG; i += 1024) vpack[i] = SENT;  // sentinel pre-fill
    __syncthreads();

    const int e0 = blockIdx.x * EPB;
    int ss[8], dd[8];
    bool ok[2];
    #pragma unroll
    for (int j = 0; j < 2; ++j) {
        const int e = e0 + (j * 1024 + t) * 4;
        ok[j] = (e < N_EDGES);
        if (ok[j]) {
            const int4 s4 = *reinterpret_cast<const int4*>(ei + e);
            const int4 d4 = *reinterpret_cast<const int4*>(ei + N_EDGES + e);
            ss[j*4+0] = s4.x; ss[j*4+1] = s4.y; ss[j*4+2] = s4.z; ss[j*4+3] = s4.w;
            dd[j*4+0] = d4.x; dd[j*4+1] = d4.y; dd[j*4+2] = d4.z; dd[j*4+3] = d4.w;
            atomicAdd(&hist[d4.x >> REG_SHIFT], 1);
            atomicAdd(&hist[d4.y >> REG_SHIFT], 1);
            atomicAdd(&hist[d4.z >> REG_SHIFT], 1);
            atomicAdd(&hist[d4.w >> REG_SHIFT], 1);
        }
    }
    __syncthreads();

    // padded exclusive scan (wave 0): section size = hist rounded up to 4
    if (t < 64) {
        const int v = (t < NREG) ? ((hist[t] + 3) & ~3) : 0;
        int s = v;
        #pragma unroll
        for (int off = 1; off < 64; off <<= 1) {
            const int u = __shfl_up(s, off, 64);
            if (t >= off) s += u;
        }
        if (t < NREG) lstart[t] = s - v;
    }
    __syncthreads();
    if (t < NREG) {
        const int h = hist[t];
        const int hres = (h + 3) & ~3;
        const int rb = (hres > 0) ? atomicAdd(&cursorR[t * CR_STRIDE], hres) : 0;
        cbase[t] = t * CAPR + rb - lstart[t];
        rankR[t] = 0;
        for (int q = h; q < hres; ++q) rbin[lstart[t] + q] = (unsigned char)t;  // pad slots
    }
    __syncthreads();

    #pragma unroll
    for (int j = 0; j < 2; ++j) {
        if (ok[j]) {
            #pragma unroll
            for (int k = 0; k < 4; ++k) {
                const int s = ss[j*4+k], d = dd[j*4+k];
                const int r = d >> REG_SHIFT;
                const int rk = atomicAdd(&rankR[r], 1);
                const int p = lstart[r] + rk;
                vpack[p] = ((unsigned int)s & 0xFFFFu) |
                           (((unsigned int)(d & 2047) | (((unsigned int)s >> 16) << 11)) << 16);
                rbin[p] = (unsigned char)r;
            }
        }
    }
    __syncthreads();

    // 16B-aligned uint4 writeout: every aligned group of 4 is one region
    const int ptot = lstart[NREG - 1] + ((hist[NREG - 1] + 3) & ~3);
    for (int i4 = t * 4; i4 < ptot; i4 += 1024 * 4) {
        const int rb = (int)rbin[i4];
        const int addr = cbase[rb] + i4;     // multiple of 4
        if (addr + 3 < (rb + 1) * CAPR)
            *reinterpret_cast<uint4*>(&ipack[addr]) =
                *reinterpret_cast<const uint4*>(&vpack[i4]);
    }
}

// ---------------------------------------------------------------------------
// K2: pass-2 with padded reservations + uint4 writeout. Skips sentinels.
// ---------------------------------------------------------------------------
__global__ __launch_bounds__(1024) void k2_pass2(
    const unsigned int* __restrict__ ipack, const int* __restrict__ cursorR,
    int* __restrict__ cursor, unsigned int* __restrict__ sorted)
{
    __shared__ unsigned int vals[EPB + 4 * REG_BINS];
    __shared__ unsigned char lbin[EPB + 4 * REG_BINS];
    __shared__ int hist[REG_BINS], lstart[REG_BINS], cbase[REG_BINS], rankB[REG_BINS];
    const int t = threadIdx.x;
    const int r = blockIdx.x / P2CH, c = blockIdx.x % P2CH;
    const int cnt_r = min(cursorR[r * CR_STRIDE], CAPR);
    const int i0 = c * EPB;
    const int ecnt = min(EPB, cnt_r - i0);
    if (ecnt <= 0) return;

    if (t < REG_BINS) hist[t] = 0;
    for (int i = t; i < EPB + 4 * REG_BINS; i += 1024) vals[i] = SENT;
    __syncthreads();

    unsigned int ent[8];
    int lb[8];
    #pragma unroll
    for (int j = 0; j < 2; ++j) {
        const int base = (j * 1024 + t) * 4;
        uint4 v4 = make_uint4(SENT, SENT, SENT, SENT);
        if (base < ecnt)
            v4 = *reinterpret_cast<const uint4*>(ipack + (size_t)r * CAPR + i0 + base);
        const unsigned int ev[4] = {v4.x, v4.y, v4.z, v4.w};
        #pragma unroll
        for (int k = 0; k < 4; ++k) {
            const int idx = base + k;
            if (idx < ecnt && ev[k] != SENT) {
                const unsigned int e = ev[k];
                const unsigned int hi = e >> 16;
                const int src = (int)(e & 0xFFFFu) | ((int)((hi >> 11) & 1u) << 16);
                const int dstloc = (int)(hi & 2047u);
                lb[j*4+k] = dstloc >> 6;
                ent[j*4+k] = (unsigned int)src | ((unsigned int)(dstloc & 63) << 24);
                atomicAdd(&hist[lb[j*4+k]], 1);
            } else lb[j*4+k] = -1;
        }
    }
    __syncthreads();

    if (t < 64) {
        const int v = (t < REG_BINS) ? ((hist[t] + 3) & ~3) : 0;
        int s = v;
        #pragma unroll
        for (int off = 1; off < 32; off <<= 1) {
            const int u = __shfl_up(s, off, 64);
            if (t >= off) s += u;
        }
        if (t < REG_BINS) lstart[t] = s - v;
    }
    __syncthreads();
    if (t < REG_BINS) {
        const int gb = r * REG_BINS + t;
        const int h = hist[t];
        const int hres = (h + 3) & ~3;
        const int rb = (hres > 0) ? atomicAdd(&cursor[gb], hres) : 0;
        cbase[t] = gb * BUCKET_CAP + rb - lstart[t];
        rankB[t] = 0;
        for (int q = h; q < hres; ++q) lbin[lstart[t] + q] = (unsigned char)t;
    }
    __syncthreads();

    #pragma unroll
    for (int j = 0; j < 8; ++j) {
        if (lb[j] >= 0) {
            const int rk = atomicAdd(&rankB[lb[j]], 1);
            const int p = lstart[lb[j]] + rk;
            vals[p] = ent[j];
            lbin[p] = (unsigned char)lb[j];
        }
    }
    __syncthreads();

    const int ptot = lstart[REG_BINS - 1] + ((hist[REG_BINS - 1] + 3) & ~3);
    for (int i4 = t * 4; i4 < ptot; i4 += 1024 * 4) {
        const int lb2 = (int)lbin[i4];
        const int addr = cbase[lb2] + i4;    // multiple of 4
        if (addr + 3 < (r * REG_BINS + lb2 + 1) * BUCKET_CAP)
            *reinterpret_cast<uint4*>(&sorted[addr]) =
                *reinterpret_cast<const uint4*>(&vals[i4]);
    }
}

// ---------------------------------------------------------------------------
// K3: aggregate (sentinel-aware) via counting sort -> atomic-free FMA.
// ---------------------------------------------------------------------------
__global__ __launch_bounds__(AGG_T) void f_aggregate_sorted(
    const unsigned int* __restrict__ sorted, const int* __restrict__ cursor,
    const float4* __restrict__ node_data, const float* __restrict__ bias,
    float* __restrict__ out)
{
    __shared__ unsigned int sortedLDS[BUCKET_CAP];
    __shared__ float part0[AGG_T], part1[AGG_T], partw[AGG_T];
    __shared__ int hist[NPB], startB[NPB], rankB[NPB];
    __shared__ float adst[NPB];
    const int b = blockIdx.x, t = threadIdx.x;

    if (t < NPB) {
        const int n = b * NPB + t;
        hist[t] = 0; rankB[t] = 0;
        adst[t] = (n < N_NODES) ? node_data[n].w : 0.f;
    }
    __syncthreads();

    const int cnt = min(cursor[b], BUCKET_CAP);
    const unsigned int* eb = sorted + (size_t)b * BUCKET_CAP;

    unsigned int pk[5];
    bool okv[5];
    #pragma unroll
    for (int j = 0; j < 5; ++j) {
        const int i = t + j * AGG_T;
        pk[j] = (i < cnt) ? eb[i] : SENT;
        okv[j] = (pk[j] != SENT);
        if (okv[j]) atomicAdd(&hist[pk[j] >> 24], 1);
    }
    __syncthreads();

    if (t < NPB) {
        const int v = hist[t];
        int s = v;
        #pragma unroll
        for (int off = 1; off < 64; off <<= 1) {
            const int u = __shfl_up(s, off, 64);
            if ((t & 63) >= off) s += u;
        }
        startB[t] = s - v;
    }
    __syncthreads();

    #pragma unroll
    for (int j = 0; j < 5; ++j) {
        if (okv[j]) {
            const int dl = (int)(pk[j] >> 24);
            const int rk = atomicAdd(&rankB[dl], 1);
            sortedLDS[startB[dl] + rk] = pk[j];
        }
    }
    __syncthreads();

    {
        const int dl = t & 63, sl = t >> 6;
        const float ad = adst[dl];
        const int rs = startB[dl], re = rs + hist[dl];
        float s0 = 0.f, s1 = 0.f, sw = 0.f;
        for (int i = rs + sl; i < re; i += 8) {
            const unsigned int p = sortedLDS[i];
            const int src = (int)(p & 0xFFFFFFu);
            const float4 nd = node_data[src];
            float a = nd.z + ad;
            a = (a >= 0.f) ? a : NEG_SLOPE * a;
            const float w = __expf(a);
            s0 += w * nd.x; s1 += w * nd.y; sw += w;
        }
        part0[t] = s0; part1[t] = s1; partw[t] = sw;
    }
    __syncthreads();

    if (t < NPB) {
        const int n = b * NPB + t;
        if (n < N_NODES) {
            float A0 = 0.f, A1 = 0.f, AW = 0.f;
            #pragma unroll
            for (int k = 0; k < 8; ++k) {
                A0 += part0[t + NPB * k];
                A1 += part1[t + NPB * k];
                AW += partw[t + NPB * k];
            }
            const float4 nd = node_data[n];
            float a = nd.z + nd.w;
            a = (a >= 0.f) ? a : NEG_SLOPE * a;
            const float w = __expf(a);
            const float den = AW + w + 1e-16f;
            const float o0 = (A0 + w * nd.x) / den + bias[0];
            const float o1 = (A1 + w * nd.y) / den + bias[1];
            *reinterpret_cast<float2*>(out + (size_t)n * 2) = make_float2(o0, o1);
        }
    }
}

// ------------------- last-resort fallback (round-2 path) -------------------
__global__ __launch_bounds__(256) void proj_kernel(
    const float* __restrict__ x, const float* __restrict__ W,
    const float* __restrict__ att_src, const float* __restrict__ att_dst,
    float4* __restrict__ node_data, float4* __restrict__ accum)
{
    const int wave = (blockIdx.x * blockDim.x + threadIdx.x) >> 6;
    const int lane = threadIdx.x & 63;
    if (wave >= N_NODES) return;
    float p0 = 0.f, p1 = 0.f;
    if (lane < 48) {
        const float4 xv = *reinterpret_cast<const float4*>(x + (size_t)wave * IN_DIM + lane * 4);
        const float* Wr = W + lane * 4 * 2;
        p0 = xv.x * Wr[0] + xv.y * Wr[2] + xv.z * Wr[4] + xv.w * Wr[6];
        p1 = xv.x * Wr[1] + xv.y * Wr[3] + xv.z * Wr[5] + xv.w * Wr[7];
    }
    #pragma unroll
    for (int off = 32; off >= 1; off >>= 1) {
        p0 += __shfl_down(p0, off, 64);
        p1 += __shfl_down(p1, off, 64);
    }
    if (lane == 0) {
        const float as = p0 * att_src[0] + p1 * att_src[1];
        const float ad = p0 * att_dst[0] + p1 * att_dst[1];
        node_data[wave] = make_float4(p0, p1, as, ad);
        if (accum) accum[wave] = make_float4(0.f, 0.f, 0.f, 0.f);
    }
}

__global__ __launch_bounds__(256) void edge_kernel_atomic(
    const int* __restrict__ ei, const float4* __restrict__ node_data,
    float* __restrict__ accum)
{
    const int t = blockIdx.x * blockDim.x + threadIdx.x;
    const int base = t * 4;
    if (base >= N_EDGES) return;
    const int4 s4 = *reinterpret_cast<const int4*>(ei + base);
    const int4 d4 = *reinterpret_cast<const int4*>(ei + N_EDGES + base);
    const int ss[4] = {s4.x, s4.y, s4.z, s4.w};
    const int dd[4] = {d4.x, d4.y, d4.z, d4.w};
    #pragma unroll
    for (int k = 0; k < 4; ++k) {
        const int s = ss[k], d = dd[k];
        const float4 nds = node_data[s];
        const float ad = reinterpret_cast<const float*>(node_data)[d * 4 + 3];
        float a = nds.z + ad;
        a = (a >= 0.f) ? a : NEG_SLOPE * a;
        const float w = __expf(a);
        atomicAdd(&accum[d * 4 + 0], w * nds.x);
        atomicAdd(&accum[d * 4 + 1], w * nds.y);
        atomicAdd(&accum[d * 4 + 2], w);
    }
}

__global__ __launch_bounds__(256) void finalize_kernel(
    const float4* __restrict__ node_data, const float4* __restrict__ accum,
    const float* __restrict__ bias, float* __restrict__ out)
{
    const int n = blockIdx.x * blockDim.x + threadIdx.x;
    if (n >= N_NODES) return;
    const float4 nd = node_data[n];
    const float4 ac = accum[n];
    float a = nd.z + nd.w;
    a = (a >= 0.f) ? a : NEG_SLOPE * a;
    const float w = __expf(a);
    const float den = ac.z + w + 1e-16f;
    const float o0 = (ac.x + w * nd.x) / den + bias[0];
    const float o1 = (ac.y + w * nd.y) / den + bias[1];
    *reinterpret_cast<float2*>(out + (size_t)n * 2) = make_float2(o0, o1);
}

extern "C" void kernel_launch(void* const* d_in, const int* in_sizes, int n_in,
                              void* d_out, int out_size, void* d_ws, size_t ws_size,
                              hipStream_t stream) {
    const float* x       = (const float*)d_in[0];
    const int*   ei      = (const int*)d_in[1];
    const float* W       = (const float*)d_in[3];
    const float* att_src = (const float*)d_in[4];
    const float* att_dst = (const float*)d_in[5];
    const float* bias    = (const float*)d_in[6];
    float* out = (float*)d_out;

    char* p = (char*)d_ws;
    float4* node_data = (float4*)p;            p += (size_t)N_NODES * 16;                 // 1.6 MB
    unsigned int* sorted = (unsigned int*)p;   p += (size_t)N_BUCKETS * BUCKET_CAP * 4;   // 16.0 MB
    unsigned int* ipack  = (unsigned int*)p;   p += (size_t)NREG * CAPR * 4;              // 14.5 MB
    int* cursorR = (int*)p;                    p += (size_t)NREG * CR_STRIDE * 4;
    int* cursor  = (int*)p;                    p += (size_t)N_BUCKETS * 4;
    const size_t need = (size_t)(p - (char*)d_ws);

    if (ws_size >= need) {
        k0_init<<<(NREG * CR_STRIDE + N_BUCKETS + 255) / 256, 256, 0, stream>>>(cursorR, cursor);
        k1_proj_pass1<<<P1BLK + PROJ_BLOCKS, 1024, 0, stream>>>(
            x, W, att_src, att_dst, node_data, ei, ipack, cursorR);
        k2_pass2<<<P2BLK, 1024, 0, stream>>>(ipack, cursorR, cursor, sorted);
        f_aggregate_sorted<<<N_BUCKETS, AGG_T, 0, stream>>>(sorted, cursor, node_data, bias, out);
    } else {
        float4* nd2 = (float4*)d_ws;
        float4* accum = nd2 + N_NODES;
        proj_kernel<<<(N_NODES + 3) / 4, 256, 0, stream>>>(x, W, att_src, att_dst, nd2, accum);
        edge_kernel_atomic<<<(N_EDGES / 4 + 255) / 256, 256, 0, stream>>>(ei, nd2, (float*)accum);
        finalize_kernel<<<(N_NODES + 255) / 256, 256, 0, stream>>>(nd2, accum, bias, out);
    }
}

// Round 16
// 71.676 us; speedup vs baseline: 1.1899x; 1.0202x over previous
//
#include <hip/hip_runtime.h>

#define N_NODES 100000
#define N_EDGES 3200000
#define IN_DIM 192
#define NEG_SLOPE 0.2f

#define BSHIFT 6
#define NPB 64
#define N_BUCKETS 1563               // ceil(100000/64)
#define BUCKET_CAP 2560              // mult of 4; mean 2048 + 5sig + pad < 2560

#define REG_SHIFT 11
#define NREG 49                      // ceil(100000/2048)
#define REG_BINS 32

#define EPB 8192
#define P1BLK ((N_EDGES + EPB - 1) / EPB)   // 391
#define SEG_PER_CH 44
#define P2CH ((P1BLK + SEG_PER_CH - 1) / SEG_PER_CH)   // 9
#define P2BLK (NREG * P2CH)                  // 441
#define BSTRIDE 64                           // boundary row stride (ints)
#define PROJ_WPB 16
#define PROJ_BLOCKS ((N_NODES + PROJ_WPB - 1) / PROJ_WPB)
#define AGG_T 512
#define SENT 0xFFFFFFFFu

__global__ __launch_bounds__(256) void k0_init(int* __restrict__ cursor)
{
    const int i = blockIdx.x * blockDim.x + threadIdx.x;
    if (i < N_BUCKETS) cursor[i] = 0;
}

// ---------------------------------------------------------------------------
// K1 (fused): blocks [0,P1BLK) = pass-1 region sort -> BLOCK-PRIVATE segment,
// PURE LINEAR uint4 stream-out (no atomics, no indirection, no padding) +
// 50-int boundary row. Blocks [P1BLK,...) = node projection.
// ipack entry: low16 = src&0xFFFF; high16 = dstloc(11b) | (src>>16)<<11.
// ---------------------------------------------------------------------------
__global__ __launch_bounds__(1024) void k1_proj_pass1(
    const float* __restrict__ x, const float* __restrict__ W,
    const float* __restrict__ att_src, const float* __restrict__ att_dst,
    float4* __restrict__ node_data, const int* __restrict__ ei,
    unsigned int* __restrict__ ipack, int* __restrict__ boundary)
{
    __shared__ unsigned int vpack[EPB];       // 32 KB
    __shared__ int hist[NREG], lstart[NREG], rankR[NREG];
    const int t = threadIdx.x;

    if (blockIdx.x >= P1BLK) {
        const int wave = (blockIdx.x - P1BLK) * PROJ_WPB + (t >> 6);
        const int lane = t & 63;
        if (wave >= N_NODES) return;
        float p0 = 0.f, p1 = 0.f;
        if (lane < 48) {
            const float4 xv = *reinterpret_cast<const float4*>(x + (size_t)wave * IN_DIM + lane * 4);
            const float* Wr = W + lane * 4 * 2;   // W is [192][2] row-major
            p0 = xv.x * Wr[0] + xv.y * Wr[2] + xv.z * Wr[4] + xv.w * Wr[6];
            p1 = xv.x * Wr[1] + xv.y * Wr[3] + xv.z * Wr[5] + xv.w * Wr[7];
        }
        #pragma unroll
        for (int off = 32; off >= 1; off >>= 1) {
            p0 += __shfl_down(p0, off, 64);
            p1 += __shfl_down(p1, off, 64);
        }
        if (lane == 0) {
            const float as = p0 * att_src[0] + p1 * att_src[1];
            const float ad = p0 * att_dst[0] + p1 * att_dst[1];
            node_data[wave] = make_float4(p0, p1, as, ad);
        }
        return;
    }

    // ---- scatter role ----
    if (t < NREG) hist[t] = 0;
    __syncthreads();

    const int e0 = blockIdx.x * EPB;
    const int ecnt = min(EPB, N_EDGES - e0);   // always a multiple of 4
    int ss[8], dd[8];
    bool ok[2];
    #pragma unroll
    for (int j = 0; j < 2; ++j) {
        const int e = e0 + (j * 1024 + t) * 4;
        ok[j] = (e < N_EDGES);
        if (ok[j]) {
            const int4 s4 = *reinterpret_cast<const int4*>(ei + e);
            const int4 d4 = *reinterpret_cast<const int4*>(ei + N_EDGES + e);
            ss[j*4+0] = s4.x; ss[j*4+1] = s4.y; ss[j*4+2] = s4.z; ss[j*4+3] = s4.w;
            dd[j*4+0] = d4.x; dd[j*4+1] = d4.y; dd[j*4+2] = d4.z; dd[j*4+3] = d4.w;
            atomicAdd(&hist[d4.x >> REG_SHIFT], 1);
            atomicAdd(&hist[d4.y >> REG_SHIFT], 1);
            atomicAdd(&hist[d4.z >> REG_SHIFT], 1);
            atomicAdd(&hist[d4.w >> REG_SHIFT], 1);
        }
    }
    __syncthreads();

    // exclusive scan over 49 regions (wave 0)
    if (t < 64) {
        const int v = (t < NREG) ? hist[t] : 0;
        int s = v;
        #pragma unroll
        for (int off = 1; off < 64; off <<= 1) {
            const int u = __shfl_up(s, off, 64);
            if (t >= off) s += u;
        }
        if (t < NREG) lstart[t] = s - v;
    }
    __syncthreads();
    if (t < NREG) rankR[t] = 0;
    // boundary row: region starts + total
    if (t < NREG) boundary[blockIdx.x * BSTRIDE + t] = lstart[t];
    if (t == NREG) boundary[blockIdx.x * BSTRIDE + NREG] = ecnt;
    __syncthreads();

    // place into LDS in region order
    #pragma unroll
    for (int j = 0; j < 2; ++j) {
        if (ok[j]) {
            #pragma unroll
            for (int k = 0; k < 4; ++k) {
                const int s = ss[j*4+k], d = dd[j*4+k];
                const int r = d >> REG_SHIFT;
                const int rk = atomicAdd(&rankR[r], 1);
                vpack[lstart[r] + rk] =
                    ((unsigned int)s & 0xFFFFu) |
                    (((unsigned int)(d & 2047) | (((unsigned int)s >> 16) << 11)) << 16);
            }
        }
    }
    __syncthreads();

    // PURE LINEAR uint4 stream-out (ecnt multiple of 4)
    for (int i4 = t * 4; i4 < ecnt; i4 += 1024 * 4)
        *reinterpret_cast<uint4*>(&ipack[e0 + i4]) =
            *reinterpret_cast<const uint4*>(&vpack[i4]);
}

// ---------------------------------------------------------------------------
// K2: block (region r, chunk c): gather region-r slices from ~44 block
// segments (boundary table + 6-step binary search), LDS sort by 32 bins,
// cursor reserve (padded), uint4 writeout with sentinels.
// ---------------------------------------------------------------------------
__global__ __launch_bounds__(1024) void k2_pass2(
    const unsigned int* __restrict__ ipack, const int* __restrict__ boundary,
    int* __restrict__ cursor, unsigned int* __restrict__ sorted)
{
    __shared__ unsigned int vals[EPB + 4 * REG_BINS];
    __shared__ unsigned char lbin[EPB + 4 * REG_BINS];
    __shared__ int spre[SEG_PER_CH + 1], sbase[SEG_PER_CH];
    __shared__ int hist[REG_BINS], lstart[REG_BINS], cbase[REG_BINS], rankB[REG_BINS];
    const int t = threadIdx.x;
    const int r = blockIdx.x / P2CH, c = blockIdx.x % P2CH;
    const int s0 = c * SEG_PER_CH;
    const int nseg = min(SEG_PER_CH, P1BLK - s0);

    if (t < REG_BINS) hist[t] = 0;
    for (int i = t; i < EPB + 4 * REG_BINS; i += 1024) vals[i] = SENT;
    __syncthreads();

    // slice bounds for this chunk (wave 0): slen -> exclusive prefix spre
    if (t < 64) {
        int len = 0;
        if (t < nseg) {
            const int seg = s0 + t;
            const int b0 = boundary[seg * BSTRIDE + r];
            const int b1 = boundary[seg * BSTRIDE + r + 1];
            len = b1 - b0;
            sbase[t] = seg * EPB + b0;
        }
        int s = len;
        #pragma unroll
        for (int off = 1; off < 64; off <<= 1) {
            const int u = __shfl_up(s, off, 64);
            if (t >= off) s += u;
        }
        if (t < nseg) spre[t] = s - len;
        if (t == nseg - 1 || (nseg < 64 && t == nseg)) spre[nseg] = (t < nseg) ? s : spre[nseg];
        if (t == nseg - 1) spre[nseg] = s;   // total
    }
    __syncthreads();
    const int total = spre[nseg];

    // gather entries: binary search segment, decode, histogram
    unsigned int ent[8];
    int lb[8];
    #pragma unroll
    for (int j = 0; j < 8; ++j) {
        const int i = t + j * 1024;
        if (i < total) {
            int lo = 0, hi = nseg - 1;
            #pragma unroll
            for (int bs = 0; bs < 6; ++bs) {
                const int mid = (lo + hi + 1) >> 1;
                if (spre[mid] <= i) lo = mid; else hi = mid - 1;
            }
            const unsigned int e = ipack[sbase[lo] + (i - spre[lo])];
            const unsigned int hi16 = e >> 16;
            const int src = (int)(e & 0xFFFFu) | ((int)((hi16 >> 11) & 1u) << 16);
            const int dstloc = (int)(hi16 & 2047u);
            lb[j] = dstloc >> 6;
            ent[j] = (unsigned int)src | ((unsigned int)(dstloc & 63) << 24);
            atomicAdd(&hist[lb[j]], 1);
        } else lb[j] = -1;
    }
    __syncthreads();

    // padded exclusive scan over 32 bins (wave 0)
    if (t < 64) {
        const int v = (t < REG_BINS) ? ((hist[t] + 3) & ~3) : 0;
        int s = v;
        #pragma unroll
        for (int off = 1; off < 32; off <<= 1) {
            const int u = __shfl_up(s, off, 64);
            if (t >= off) s += u;
        }
        if (t < REG_BINS) lstart[t] = s - v;
    }
    __syncthreads();
    if (t < REG_BINS) {
        const int gb = r * REG_BINS + t;
        const int h = hist[t];
        const int hres = (h + 3) & ~3;
        const int rb = (hres > 0 && gb < N_BUCKETS) ? atomicAdd(&cursor[gb], hres) : 0;
        cbase[t] = gb * BUCKET_CAP + rb - lstart[t];
        rankB[t] = 0;
        for (int q = h; q < hres; ++q) lbin[lstart[t] + q] = (unsigned char)t;
    }
    __syncthreads();

    #pragma unroll
    for (int j = 0; j < 8; ++j) {
        if (lb[j] >= 0) {
            const int rk = atomicAdd(&rankB[lb[j]], 1);
            const int p = lstart[lb[j]] + rk;
            vals[p] = ent[j];
            lbin[p] = (unsigned char)lb[j];
        }
    }
    __syncthreads();

    const int ptot = lstart[REG_BINS - 1] + ((hist[REG_BINS - 1] + 3) & ~3);
    for (int i4 = t * 4; i4 < ptot; i4 += 1024 * 4) {
        const int lb2 = (int)lbin[i4];
        const int addr = cbase[lb2] + i4;    // multiple of 4
        if (addr + 3 < (r * REG_BINS + lb2 + 1) * BUCKET_CAP)
            *reinterpret_cast<uint4*>(&sorted[addr]) =
                *reinterpret_cast<const uint4*>(&vals[i4]);
    }
}

// ---------------------------------------------------------------------------
// K3: aggregate (sentinel-aware) via counting sort -> atomic-free FMA.
// ---------------------------------------------------------------------------
__global__ __launch_bounds__(AGG_T) void f_aggregate_sorted(
    const unsigned int* __restrict__ sorted, const int* __restrict__ cursor,
    const float4* __restrict__ node_data, const float* __restrict__ bias,
    float* __restrict__ out)
{
    __shared__ unsigned int sortedLDS[BUCKET_CAP];
    __shared__ float part0[AGG_T], part1[AGG_T], partw[AGG_T];
    __shared__ int hist[NPB], startB[NPB], rankB[NPB];
    __shared__ float adst[NPB];
    const int b = blockIdx.x, t = threadIdx.x;

    if (t < NPB) {
        const int n = b * NPB + t;
        hist[t] = 0; rankB[t] = 0;
        adst[t] = (n < N_NODES) ? node_data[n].w : 0.f;
    }
    __syncthreads();

    const int cnt = min(cursor[b], BUCKET_CAP);
    const unsigned int* eb = sorted + (size_t)b * BUCKET_CAP;

    unsigned int pk[5];
    bool okv[5];
    #pragma unroll
    for (int j = 0; j < 5; ++j) {
        const int i = t + j * AGG_T;
        pk[j] = (i < cnt) ? eb[i] : SENT;
        okv[j] = (pk[j] != SENT);
        if (okv[j]) atomicAdd(&hist[pk[j] >> 24], 1);
    }
    __syncthreads();

    if (t < NPB) {
        const int v = hist[t];
        int s = v;
        #pragma unroll
        for (int off = 1; off < 64; off <<= 1) {
            const int u = __shfl_up(s, off, 64);
            if ((t & 63) >= off) s += u;
        }
        startB[t] = s - v;
    }
    __syncthreads();

    #pragma unroll
    for (int j = 0; j < 5; ++j) {
        if (okv[j]) {
            const int dl = (int)(pk[j] >> 24);
            const int rk = atomicAdd(&rankB[dl], 1);
            sortedLDS[startB[dl] + rk] = pk[j];
        }
    }
    __syncthreads();

    {
        const int dl = t & 63, sl = t >> 6;
        const float ad = adst[dl];
        const int rs = startB[dl], re = rs + hist[dl];
        float s0 = 0.f, s1 = 0.f, sw = 0.f;
        for (int i = rs + sl; i < re; i += 8) {
            const unsigned int p = sortedLDS[i];
            const int src = (int)(p & 0xFFFFFFu);
            const float4 nd = node_data[src];
            float a = nd.z + ad;
            a = (a >= 0.f) ? a : NEG_SLOPE * a;
            const float w = __expf(a);
            s0 += w * nd.x; s1 += w * nd.y; sw += w;
        }
        part0[t] = s0; part1[t] = s1; partw[t] = sw;
    }
    __syncthreads();

    if (t < NPB) {
        const int n = b * NPB + t;
        if (n < N_NODES) {
            float A0 = 0.f, A1 = 0.f, AW = 0.f;
            #pragma unroll
            for (int k = 0; k < 8; ++k) {
                A0 += part0[t + NPB * k];
                A1 += part1[t + NPB * k];
                AW += partw[t + NPB * k];
            }
            const float4 nd = node_data[n];
            float a = nd.z + nd.w;
            a = (a >= 0.f) ? a : NEG_SLOPE * a;
            const float w = __expf(a);
            const float den = AW + w + 1e-16f;
            const float o0 = (A0 + w * nd.x) / den + bias[0];
            const float o1 = (A1 + w * nd.y) / den + bias[1];
            *reinterpret_cast<float2*>(out + (size_t)n * 2) = make_float2(o0, o1);
        }
    }
}

// ------------------- last-resort fallback (round-2 path) -------------------
__global__ __launch_bounds__(256) void proj_kernel(
    const float* __restrict__ x, const float* __restrict__ W,
    const float* __restrict__ att_src, const float* __restrict__ att_dst,
    float4* __restrict__ node_data, float4* __restrict__ accum)
{
    const int wave = (blockIdx.x * blockDim.x + threadIdx.x) >> 6;
    const int lane = threadIdx.x & 63;
    if (wave >= N_NODES) return;
    float p0 = 0.f, p1 = 0.f;
    if (lane < 48) {
        const float4 xv = *reinterpret_cast<const float4*>(x + (size_t)wave * IN_DIM + lane * 4);
        const float* Wr = W + lane * 4 * 2;
        p0 = xv.x * Wr[0] + xv.y * Wr[2] + xv.z * Wr[4] + xv.w * Wr[6];
        p1 = xv.x * Wr[1] + xv.y * Wr[3] + xv.z * Wr[5] + xv.w * Wr[7];
    }
    #pragma unroll
    for (int off = 32; off >= 1; off >>= 1) {
        p0 += __shfl_down(p0, off, 64);
        p1 += __shfl_down(p1, off, 64);
    }
    if (lane == 0) {
        const float as = p0 * att_src[0] + p1 * att_src[1];
        const float ad = p0 * att_dst[0] + p1 * att_dst[1];
        node_data[wave] = make_float4(p0, p1, as, ad);
        if (accum) accum[wave] = make_float4(0.f, 0.f, 0.f, 0.f);
    }
}

__global__ __launch_bounds__(256) void edge_kernel_atomic(
    const int* __restrict__ ei, const float4* __restrict__ node_data,
    float* __restrict__ accum)
{
    const int t = blockIdx.x * blockDim.x + threadIdx.x;
    const int base = t * 4;
    if (base >= N_EDGES) return;
    const int4 s4 = *reinterpret_cast<const int4*>(ei + base);
    const int4 d4 = *reinterpret_cast<const int4*>(ei + N_EDGES + base);
    const int ss[4] = {s4.x, s4.y, s4.z, s4.w};
    const int dd[4] = {d4.x, d4.y, d4.z, d4.w};
    #pragma unroll
    for (int k = 0; k < 4; ++k) {
        const int s = ss[k], d = dd[k];
        const float4 nds = node_data[s];
        const float ad = reinterpret_cast<const float*>(node_data)[d * 4 + 3];
        float a = nds.z + ad;
        a = (a >= 0.f) ? a : NEG_SLOPE * a;
        const float w = __expf(a);
        atomicAdd(&accum[d * 4 + 0], w * nds.x);
        atomicAdd(&accum[d * 4 + 1], w * nds.y);
        atomicAdd(&accum[d * 4 + 2], w);
    }
}

__global__ __launch_bounds__(256) void finalize_kernel(
    const float4* __restrict__ node_data, const float4* __restrict__ accum,
    const float* __restrict__ bias, float* __restrict__ out)
{
    const int n = blockIdx.x * blockDim.x + threadIdx.x;
    if (n >= N_NODES) return;
    const float4 nd = node_data[n];
    const float4 ac = accum[n];
    float a = nd.z + nd.w;
    a = (a >= 0.f) ? a : NEG_SLOPE * a;
    const float w = __expf(a);
    const float den = ac.z + w + 1e-16f;
    const float o0 = (ac.x + w * nd.x) / den + bias[0];
    const float o1 = (ac.y + w * nd.y) / den + bias[1];
    *reinterpret_cast<float2*>(out + (size_t)n * 2) = make_float2(o0, o1);
}

extern "C" void kernel_launch(void* const* d_in, const int* in_sizes, int n_in,
                              void* d_out, int out_size, void* d_ws, size_t ws_size,
                              hipStream_t stream) {
    const float* x       = (const float*)d_in[0];
    const int*   ei      = (const int*)d_in[1];
    const float* W       = (const float*)d_in[3];
    const float* att_src = (const float*)d_in[4];
    const float* att_dst = (const float*)d_in[5];
    const float* bias    = (const float*)d_in[6];
    float* out = (float*)d_out;

    char* p = (char*)d_ws;
    float4* node_data = (float4*)p;            p += (size_t)N_NODES * 16;                 // 1.6 MB
    unsigned int* sorted = (unsigned int*)p;   p += (size_t)N_BUCKETS * BUCKET_CAP * 4;   // 16.0 MB
    unsigned int* ipack  = (unsigned int*)p;   p += (size_t)P1BLK * EPB * 4;              // 12.8 MB
    int* boundary = (int*)p;                   p += (size_t)P1BLK * BSTRIDE * 4;          // 100 KB
    int* cursor   = (int*)p;                   p += (size_t)N_BUCKETS * 4;
    const size_t need = (size_t)(p - (char*)d_ws);

    if (ws_size >= need) {
        k0_init<<<(N_BUCKETS + 255) / 256, 256, 0, stream>>>(cursor);
        k1_proj_pass1<<<P1BLK + PROJ_BLOCKS, 1024, 0, stream>>>(
            x, W, att_src, att_dst, node_data, ei, ipack, boundary);
        k2_pass2<<<P2BLK, 1024, 0, stream>>>(ipack, boundary, cursor, sorted);
        f_aggregate_sorted<<<N_BUCKETS, AGG_T, 0, stream>>>(sorted, cursor, node_data, bias, out);
    } else {
        float4* nd2 = (float4*)d_ws;
        float4* accum = nd2 + N_NODES;
        proj_kernel<<<(N_NODES + 3) / 4, 256, 0, stream>>>(x, W, att_src, att_dst, nd2, accum);
        edge_kernel_atomic<<<(N_EDGES / 4 + 255) / 256, 256, 0, stream>>>(ei, nd2, (float*)accum);
        finalize_kernel<<<(N_NODES + 255) / 256, 256, 0, stream>>>(nd2, accum, bias, out);
    }
}

// Round 17
// 59.731 us; speedup vs baseline: 1.4278x; 1.2000x over previous
//
#include <hip/hip_runtime.h>

#define N_NODES 100000
#define N_EDGES 3200000
#define IN_DIM 192
#define NEG_SLOPE 0.2f

// regions: 256 nodes; pass-2 block = one region (merged sort + aggregate)
#define RSH 8
#define NPR 256                      // nodes per region
#define NREG2 391                    // ceil(100000/256)
#define EPB 8192
#define P1BLK ((N_EDGES + EPB - 1) / EPB)   // 391
#define BST 392                      // boundary row: 391 starts + ecnt
#define CAP2 9216                    // region capacity (mean 8184, sigma ~90)
#define PROJ_WPB 16
#define PROJ_BLOCKS ((N_NODES + PROJ_WPB - 1) / PROJ_WPB)

// ---------------------------------------------------------------------------
// K1 (fused): blocks [0,P1BLK) = pass-1 sort of 8192 edges into 391 regions,
// block-private segment, pure linear uint4 streamout + boundary row.
// Blocks [P1BLK,...) = node projection. Entry = src<<8 | (dst & 255).
// ---------------------------------------------------------------------------
__global__ __launch_bounds__(1024) void k1_proj_pass1(
    const float* __restrict__ x, const float* __restrict__ W,
    const float* __restrict__ att_src, const float* __restrict__ att_dst,
    float4* __restrict__ node_data, const int* __restrict__ ei,
    unsigned int* __restrict__ ipack, int* __restrict__ boundary)
{
    __shared__ unsigned int vpack[EPB];       // 32 KB
    __shared__ int hist[NREG2], lstart[NREG2], rankR[NREG2];
    __shared__ int scanbuf[512];
    const int t = threadIdx.x;

    if (blockIdx.x >= P1BLK) {
        // ---------------- projection role: one 64-lane wave per node -------
        const int wave = (blockIdx.x - P1BLK) * PROJ_WPB + (t >> 6);
        const int lane = t & 63;
        if (wave >= N_NODES) return;
        float p0 = 0.f, p1 = 0.f;
        if (lane < 48) {
            const float4 xv = *reinterpret_cast<const float4*>(x + (size_t)wave * IN_DIM + lane * 4);
            const float* Wr = W + lane * 4 * 2;   // W is [192][2] row-major
            p0 = xv.x * Wr[0] + xv.y * Wr[2] + xv.z * Wr[4] + xv.w * Wr[6];
            p1 = xv.x * Wr[1] + xv.y * Wr[3] + xv.z * Wr[5] + xv.w * Wr[7];
        }
        #pragma unroll
        for (int off = 32; off >= 1; off >>= 1) {
            p0 += __shfl_down(p0, off, 64);
            p1 += __shfl_down(p1, off, 64);
        }
        if (lane == 0) {
            const float as = p0 * att_src[0] + p1 * att_src[1];
            const float ad = p0 * att_dst[0] + p1 * att_dst[1];
            node_data[wave] = make_float4(p0, p1, as, ad);
        }
        return;
    }

    // ---- pass-1 sort role ----
    for (int i = t; i < NREG2; i += 1024) hist[i] = 0;
    __syncthreads();

    const int e0 = blockIdx.x * EPB;
    const int ecnt = min(EPB, N_EDGES - e0);   // multiple of 4
    int ss[8], dd[8];
    bool ok[2];
    #pragma unroll
    for (int j = 0; j < 2; ++j) {
        const int e = e0 + (j * 1024 + t) * 4;
        ok[j] = (e < N_EDGES);
        if (ok[j]) {
            const int4 s4 = *reinterpret_cast<const int4*>(ei + e);
            const int4 d4 = *reinterpret_cast<const int4*>(ei + N_EDGES + e);
            ss[j*4+0] = s4.x; ss[j*4+1] = s4.y; ss[j*4+2] = s4.z; ss[j*4+3] = s4.w;
            dd[j*4+0] = d4.x; dd[j*4+1] = d4.y; dd[j*4+2] = d4.z; dd[j*4+3] = d4.w;
            atomicAdd(&hist[d4.x >> RSH], 1);
            atomicAdd(&hist[d4.y >> RSH], 1);
            atomicAdd(&hist[d4.z >> RSH], 1);
            atomicAdd(&hist[d4.w >> RSH], 1);
        }
    }
    __syncthreads();

    // block-wide inclusive scan over 512 (padded) -> exclusive lstart
    if (t < 512) scanbuf[t] = (t < NREG2) ? hist[t] : 0;
    __syncthreads();
    #pragma unroll
    for (int off = 1; off < 512; off <<= 1) {
        int y = 0;
        if (t < 512 && t >= off) y = scanbuf[t - off];
        __syncthreads();
        if (t < 512) scanbuf[t] += y;
        __syncthreads();
    }
    if (t < NREG2) {
        lstart[t] = scanbuf[t] - hist[t];
        rankR[t] = 0;
        boundary[blockIdx.x * BST + t] = scanbuf[t] - hist[t];
    }
    if (t == NREG2) boundary[blockIdx.x * BST + NREG2] = ecnt;
    __syncthreads();

    // place into LDS in region order
    #pragma unroll
    for (int j = 0; j < 2; ++j) {
        if (ok[j]) {
            #pragma unroll
            for (int k = 0; k < 4; ++k) {
                const int s = ss[j*4+k], d = dd[j*4+k];
                const int r = d >> RSH;
                const int rk = atomicAdd(&rankR[r], 1);
                vpack[lstart[r] + rk] = ((unsigned int)s << 8) | (unsigned int)(d & 255);
            }
        }
    }
    __syncthreads();

    // pure linear uint4 stream-out
    for (int i4 = t * 4; i4 < ecnt; i4 += 1024 * 4)
        *reinterpret_cast<uint4*>(&ipack[e0 + i4]) =
            *reinterpret_cast<const uint4*>(&vpack[i4]);
}

// ---------------------------------------------------------------------------
// K2 (merged pass-2 + aggregate): one block per 256-node region.
// Gather region slices from 391 segments (binary search), counting-sort by
// node in LDS, atomic-free register accumulation, finalize + write out.
// ---------------------------------------------------------------------------
__global__ __launch_bounds__(1024) void k2_region_agg(
    const unsigned int* __restrict__ ipack, const int* __restrict__ boundary,
    const float4* __restrict__ node_data, const float* __restrict__ bias,
    float* __restrict__ out)
{
    __shared__ unsigned int vals[CAP2];        // 36 KB (src per entry)
    __shared__ int spre[P1BLK + 1];            // exclusive prefix + total
    __shared__ int sbase[P1BLK];
    __shared__ int scanbuf[512];
    __shared__ int histN[NPR], startN[NPR], rankN[NPR];
    __shared__ float adst[NPR];
    __shared__ float part0[1024], part1[1024], partw[1024];  // 12 KB
    const int r = blockIdx.x, t = threadIdx.x;

    if (t < NPR) {
        const int n = r * NPR + t;
        histN[t] = 0; rankN[t] = 0;
        adst[t] = (n < N_NODES) ? node_data[n].w : 0.f;
    }
    int mylen = 0;
    if (t < P1BLK) {
        const int b0 = boundary[t * BST + r];
        const int b1 = boundary[t * BST + r + 1];
        mylen = b1 - b0;
        sbase[t] = t * EPB + b0;
    }
    if (t < 512) scanbuf[t] = (t < P1BLK) ? mylen : 0;
    __syncthreads();
    #pragma unroll
    for (int off = 1; off < 512; off <<= 1) {
        int y = 0;
        if (t < 512 && t >= off) y = scanbuf[t - off];
        __syncthreads();
        if (t < 512) scanbuf[t] += y;
        __syncthreads();
    }
    if (t <= P1BLK) spre[t] = (t == 0) ? 0 : scanbuf[t - 1];
    __syncthreads();
    const int total = min(spre[P1BLK], CAP2);

    // gather: binary-search segment, decode, histogram by node
    unsigned int ent[9];
    int nl[9];
    #pragma unroll
    for (int j = 0; j < 9; ++j) {
        const int i = t + j * 1024;
        if (i < total) {
            int lo = 0, hi = P1BLK - 1;
            #pragma unroll
            for (int bs = 0; bs < 9; ++bs) {
                const int mid = (lo + hi + 1) >> 1;
                if (spre[mid] <= i) lo = mid; else hi = mid - 1;
            }
            const unsigned int e = ipack[sbase[lo] + (i - spre[lo])];
            ent[j] = e >> 8;                 // src
            nl[j]  = (int)(e & 255u);        // node-local
            atomicAdd(&histN[nl[j]], 1);
        } else nl[j] = -1;
    }
    __syncthreads();

    // exclusive scan of histN (256) by wave 0, 4 chunks with carry
    if (t < 64) {
        int carry = 0;
        #pragma unroll
        for (int c2 = 0; c2 < 4; ++c2) {
            const int idx = c2 * 64 + t;
            const int v = histN[idx];
            int s = v;
            #pragma unroll
            for (int off = 1; off < 64; off <<= 1) {
                const int u = __shfl_up(s, off, 64);
                if (t >= off) s += u;
            }
            startN[idx] = carry + s - v;
            carry += __shfl(s, 63, 64);
        }
    }
    __syncthreads();

    // place srcs grouped by node
    #pragma unroll
    for (int j = 0; j < 9; ++j) {
        if (nl[j] >= 0) {
            const int rk = atomicAdd(&rankN[nl[j]], 1);
            vals[startN[nl[j]] + rk] = ent[j];
        }
    }
    __syncthreads();

    // atomic-free accumulate: thread t owns node t&255, slice t>>8 (4 slices)
    {
        const int node = t & 255, sl = t >> 8;
        const float ad = adst[node];
        const int rs = startN[node], re = rs + histN[node];
        float s0 = 0.f, s1 = 0.f, sw = 0.f;
        for (int i = rs + sl; i < re; i += 4) {
            const int src = (int)vals[i];
            const float4 nd = node_data[src];
            float a = nd.z + ad;
            a = (a >= 0.f) ? a : NEG_SLOPE * a;
            const float w = __expf(a);
            s0 += w * nd.x; s1 += w * nd.y; sw += w;
        }
        part0[t] = s0; part1[t] = s1; partw[t] = sw;
    }
    __syncthreads();

    // merge 4 slices + self-loop + bias, coalesced write
    if (t < NPR) {
        const int n = r * NPR + t;
        if (n < N_NODES) {
            const float A0 = part0[t] + part0[t + 256] + part0[t + 512] + part0[t + 768];
            const float A1 = part1[t] + part1[t + 256] + part1[t + 512] + part1[t + 768];
            const float AW = partw[t] + partw[t + 256] + partw[t + 512] + partw[t + 768];
            const float4 nd = node_data[n];
            float a = nd.z + nd.w;               // self-loop logit
            a = (a >= 0.f) ? a : NEG_SLOPE * a;
            const float w = __expf(a);
            const float den = AW + w + 1e-16f;
            const float o0 = (A0 + w * nd.x) / den + bias[0];
            const float o1 = (A1 + w * nd.y) / den + bias[1];
            *reinterpret_cast<float2*>(out + (size_t)n * 2) = make_float2(o0, o1);
        }
    }
}

// ------------------- last-resort fallback (round-2 path) -------------------
__global__ __launch_bounds__(256) void proj_kernel(
    const float* __restrict__ x, const float* __restrict__ W,
    const float* __restrict__ att_src, const float* __restrict__ att_dst,
    float4* __restrict__ node_data, float4* __restrict__ accum)
{
    const int wave = (blockIdx.x * blockDim.x + threadIdx.x) >> 6;
    const int lane = threadIdx.x & 63;
    if (wave >= N_NODES) return;
    float p0 = 0.f, p1 = 0.f;
    if (lane < 48) {
        const float4 xv = *reinterpret_cast<const float4*>(x + (size_t)wave * IN_DIM + lane * 4);
        const float* Wr = W + lane * 4 * 2;
        p0 = xv.x * Wr[0] + xv.y * Wr[2] + xv.z * Wr[4] + xv.w * Wr[6];
        p1 = xv.x * Wr[1] + xv.y * Wr[3] + xv.z * Wr[5] + xv.w * Wr[7];
    }
    #pragma unroll
    for (int off = 32; off >= 1; off >>= 1) {
        p0 += __shfl_down(p0, off, 64);
        p1 += __shfl_down(p1, off, 64);
    }
    if (lane == 0) {
        const float as = p0 * att_src[0] + p1 * att_src[1];
        const float ad = p0 * att_dst[0] + p1 * att_dst[1];
        node_data[wave] = make_float4(p0, p1, as, ad);
        if (accum) accum[wave] = make_float4(0.f, 0.f, 0.f, 0.f);
    }
}

__global__ __launch_bounds__(256) void edge_kernel_atomic(
    const int* __restrict__ ei, const float4* __restrict__ node_data,
    float* __restrict__ accum)
{
    const int t = blockIdx.x * blockDim.x + threadIdx.x;
    const int base = t * 4;
    if (base >= N_EDGES) return;
    const int4 s4 = *reinterpret_cast<const int4*>(ei + base);
    const int4 d4 = *reinterpret_cast<const int4*>(ei + N_EDGES + base);
    const int ss[4] = {s4.x, s4.y, s4.z, s4.w};
    const int dd[4] = {d4.x, d4.y, d4.z, d4.w};
    #pragma unroll
    for (int k = 0; k < 4; ++k) {
        const int s = ss[k], d = dd[k];
        const float4 nds = node_data[s];
        const float ad = reinterpret_cast<const float*>(node_data)[d * 4 + 3];
        float a = nds.z + ad;
        a = (a >= 0.f) ? a : NEG_SLOPE * a;
        const float w = __expf(a);
        atomicAdd(&accum[d * 4 + 0], w * nds.x);
        atomicAdd(&accum[d * 4 + 1], w * nds.y);
        atomicAdd(&accum[d * 4 + 2], w);
    }
}

__global__ __launch_bounds__(256) void finalize_kernel(
    const float4* __restrict__ node_data, const float4* __restrict__ accum,
    const float* __restrict__ bias, float* __restrict__ out)
{
    const int n = blockIdx.x * blockDim.x + threadIdx.x;
    if (n >= N_NODES) return;
    const float4 nd = node_data[n];
    const float4 ac = accum[n];
    float a = nd.z + nd.w;
    a = (a >= 0.f) ? a : NEG_SLOPE * a;
    const float w = __expf(a);
    const float den = ac.z + w + 1e-16f;
    const float o0 = (ac.x + w * nd.x) / den + bias[0];
    const float o1 = (ac.y + w * nd.y) / den + bias[1];
    *reinterpret_cast<float2*>(out + (size_t)n * 2) = make_float2(o0, o1);
}

extern "C" void kernel_launch(void* const* d_in, const int* in_sizes, int n_in,
                              void* d_out, int out_size, void* d_ws, size_t ws_size,
                              hipStream_t stream) {
    const float* x       = (const float*)d_in[0];
    const int*   ei      = (const int*)d_in[1];
    const float* W       = (const float*)d_in[3];
    const float* att_src = (const float*)d_in[4];
    const float* att_dst = (const float*)d_in[5];
    const float* bias    = (const float*)d_in[6];
    float* out = (float*)d_out;

    char* p = (char*)d_ws;
    float4* node_data = (float4*)p;            p += (size_t)N_NODES * 16;        // 1.6 MB
    unsigned int* ipack = (unsigned int*)p;    p += (size_t)P1BLK * EPB * 4;     // 12.8 MB
    int* boundary = (int*)p;                   p += (size_t)P1BLK * BST * 4;     // 613 KB
    const size_t need = (size_t)(p - (char*)d_ws);

    if (ws_size >= need) {
        k1_proj_pass1<<<P1BLK + PROJ_BLOCKS, 1024, 0, stream>>>(
            x, W, att_src, att_dst, node_data, ei, ipack, boundary);
        k2_region_agg<<<NREG2, 1024, 0, stream>>>(ipack, boundary, node_data, bias, out);
    } else {
        float4* nd2 = (float4*)d_ws;
        float4* accum = nd2 + N_NODES;
        proj_kernel<<<(N_NODES + 3) / 4, 256, 0, stream>>>(x, W, att_src, att_dst, nd2, accum);
        edge_kernel_atomic<<<(N_EDGES / 4 + 255) / 256, 256, 0, stream>>>(ei, nd2, (float*)accum);
        finalize_kernel<<<(N_NODES + 255) / 256, 256, 0, stream>>>(nd2, accum, bias, out);
    }
}

// Round 18
// 58.399 us; speedup vs baseline: 1.4604x; 1.0228x over previous
//
#include <hip/hip_runtime.h>

#define N_NODES 100000
#define N_EDGES 3200000
#define IN_DIM 192
#define NEG_SLOPE 0.2f

// regions: 256 nodes; pass-2 block = one region (merged sort + aggregate)
#define RSH 8
#define NPR 256                      // nodes per region
#define NREG2 391                    // ceil(100000/256)
#define EPB 8192
#define P1BLK ((N_EDGES + EPB - 1) / EPB)   // 391
#define BST 392                      // boundary row: 391 starts + ecnt
#define CAP2 9216                    // region capacity (mean 8184, sigma ~90)
#define PROJ_WPB 16
#define PROJ_BLOCKS ((N_NODES + PROJ_WPB - 1) / PROJ_WPB)

// ---------------------------------------------------------------------------
// K1 (fused): blocks [0,P1BLK) = pass-1 sort of 8192 edges into 391 regions,
// block-private segment, pure linear uint4 streamout + boundary row.
// Scan over 391 bins via ONE WAVE (7 chunks, shfl) - no block barriers.
// Blocks [P1BLK,...) = node projection. Entry = src<<8 | (dst & 255).
// ---------------------------------------------------------------------------
__global__ __launch_bounds__(1024) void k1_proj_pass1(
    const float* __restrict__ x, const float* __restrict__ W,
    const float* __restrict__ att_src, const float* __restrict__ att_dst,
    float4* __restrict__ node_data, const int* __restrict__ ei,
    unsigned int* __restrict__ ipack, int* __restrict__ boundary)
{
    __shared__ unsigned int vpack[EPB];       // 32 KB
    __shared__ int hist[NREG2], lstart[NREG2], rankR[NREG2];
    const int t = threadIdx.x;

    if (blockIdx.x >= P1BLK) {
        // ---------------- projection role: one 64-lane wave per node -------
        const int wave = (blockIdx.x - P1BLK) * PROJ_WPB + (t >> 6);
        const int lane = t & 63;
        if (wave >= N_NODES) return;
        float p0 = 0.f, p1 = 0.f;
        if (lane < 48) {
            const float4 xv = *reinterpret_cast<const float4*>(x + (size_t)wave * IN_DIM + lane * 4);
            const float* Wr = W + lane * 4 * 2;   // W is [192][2] row-major
            p0 = xv.x * Wr[0] + xv.y * Wr[2] + xv.z * Wr[4] + xv.w * Wr[6];
            p1 = xv.x * Wr[1] + xv.y * Wr[3] + xv.z * Wr[5] + xv.w * Wr[7];
        }
        #pragma unroll
        for (int off = 32; off >= 1; off >>= 1) {
            p0 += __shfl_down(p0, off, 64);
            p1 += __shfl_down(p1, off, 64);
        }
        if (lane == 0) {
            const float as = p0 * att_src[0] + p1 * att_src[1];
            const float ad = p0 * att_dst[0] + p1 * att_dst[1];
            node_data[wave] = make_float4(p0, p1, as, ad);
        }
        return;
    }

    // ---- pass-1 sort role ----
    for (int i = t; i < NREG2; i += 1024) hist[i] = 0;
    __syncthreads();

    const int e0 = blockIdx.x * EPB;
    const int ecnt = min(EPB, N_EDGES - e0);   // multiple of 4
    int ss[8], dd[8];
    bool ok[2];
    #pragma unroll
    for (int j = 0; j < 2; ++j) {
        const int e = e0 + (j * 1024 + t) * 4;
        ok[j] = (e < N_EDGES);
        if (ok[j]) {
            const int4 s4 = *reinterpret_cast<const int4*>(ei + e);
            const int4 d4 = *reinterpret_cast<const int4*>(ei + N_EDGES + e);
            ss[j*4+0] = s4.x; ss[j*4+1] = s4.y; ss[j*4+2] = s4.z; ss[j*4+3] = s4.w;
            dd[j*4+0] = d4.x; dd[j*4+1] = d4.y; dd[j*4+2] = d4.z; dd[j*4+3] = d4.w;
            atomicAdd(&hist[d4.x >> RSH], 1);
            atomicAdd(&hist[d4.y >> RSH], 1);
            atomicAdd(&hist[d4.z >> RSH], 1);
            atomicAdd(&hist[d4.w >> RSH], 1);
        }
    }
    __syncthreads();

    // single-wave exclusive scan over 391 bins (7 chunks of 64, carry)
    if (t < 64) {
        int carry = 0;
        #pragma unroll
        for (int c = 0; c < 7; ++c) {
            const int idx = c * 64 + t;
            const int v = (idx < NREG2) ? hist[idx] : 0;
            int s = v;
            #pragma unroll
            for (int off = 1; off < 64; off <<= 1) {
                const int u = __shfl_up(s, off, 64);
                if (t >= off) s += u;
            }
            if (idx < NREG2) lstart[idx] = carry + s - v;
            carry += __shfl(s, 63, 64);
        }
    }
    __syncthreads();
    if (t < NREG2) {
        rankR[t] = 0;
        boundary[blockIdx.x * BST + t] = lstart[t];
    }
    if (t == NREG2) boundary[blockIdx.x * BST + NREG2] = ecnt;
    __syncthreads();

    // place into LDS in region order
    #pragma unroll
    for (int j = 0; j < 2; ++j) {
        if (ok[j]) {
            #pragma unroll
            for (int k = 0; k < 4; ++k) {
                const int s = ss[j*4+k], d = dd[j*4+k];
                const int r = d >> RSH;
                const int rk = atomicAdd(&rankR[r], 1);
                vpack[lstart[r] + rk] = ((unsigned int)s << 8) | (unsigned int)(d & 255);
            }
        }
    }
    __syncthreads();

    // pure linear uint4 stream-out
    for (int i4 = t * 4; i4 < ecnt; i4 += 1024 * 4)
        *reinterpret_cast<uint4*>(&ipack[e0 + i4]) =
            *reinterpret_cast<const uint4*>(&vpack[i4]);
}

// ---------------------------------------------------------------------------
// K2 (merged pass-2 + aggregate): one block per 256-node region.
// Segment prefix via ONE WAVE; address-table fill into vals[] (reused LDS)
// replaces per-entry binary search; counting-sort by node; atomic-free
// register accumulation; finalize + write out.
// ---------------------------------------------------------------------------
__global__ __launch_bounds__(1024) void k2_region_agg(
    const unsigned int* __restrict__ ipack, const int* __restrict__ boundary,
    const float4* __restrict__ node_data, const float* __restrict__ bias,
    float* __restrict__ out)
{
    __shared__ unsigned int vals[CAP2];        // 36 KB: addr table, then srcs
    __shared__ int slen[P1BLK], sbase[P1BLK];
    __shared__ int spre[P1BLK + 1];
    __shared__ int histN[NPR], startN[NPR], rankN[NPR];
    __shared__ float adst[NPR];
    __shared__ float part0[1024], part1[1024], partw[1024];  // 12 KB
    const int r = blockIdx.x, t = threadIdx.x;

    if (t < NPR) {
        const int n = r * NPR + t;
        histN[t] = 0; rankN[t] = 0;
        adst[t] = (n < N_NODES) ? node_data[n].w : 0.f;
    }
    if (t < P1BLK) {
        const int b0 = boundary[t * BST + r];
        const int b1 = boundary[t * BST + r + 1];
        slen[t]  = b1 - b0;
        sbase[t] = t * EPB + b0;
    }
    __syncthreads();

    // single-wave exclusive prefix over 391 segment lengths
    if (t < 64) {
        int carry = 0;
        #pragma unroll
        for (int c = 0; c < 7; ++c) {
            const int idx = c * 64 + t;
            const int v = (idx < P1BLK) ? slen[idx] : 0;
            int s = v;
            #pragma unroll
            for (int off = 1; off < 64; off <<= 1) {
                const int u = __shfl_up(s, off, 64);
                if (t >= off) s += u;
            }
            if (idx < P1BLK) spre[idx] = carry + s - v;
            carry += __shfl(s, 63, 64);
        }
        if (t == 0) spre[P1BLK] = carry;
    }
    __syncthreads();
    const int total = min(spre[P1BLK], CAP2);

    // fill address table: vals[i] = global ipack index for entry i
    for (int s2 = t; s2 < P1BLK; s2 += 1024) {
        int b0 = spre[s2];
        int len = slen[s2];
        if (b0 < CAP2) {
            if (b0 + len > CAP2) len = CAP2 - b0;
            const int gb = sbase[s2];
            for (int k = 0; k < len; ++k) vals[b0 + k] = (unsigned int)(gb + k);
        }
    }
    __syncthreads();

    // gather via address table, decode, histogram by node
    unsigned int ent[9];
    int nl[9];
    #pragma unroll
    for (int j = 0; j < 9; ++j) {
        const int i = t + j * 1024;
        if (i < total) {
            const unsigned int e = ipack[vals[i]];
            ent[j] = e >> 8;                 // src
            nl[j]  = (int)(e & 255u);        // node-local
            atomicAdd(&histN[nl[j]], 1);
        } else nl[j] = -1;
    }
    __syncthreads();

    // exclusive scan of histN (256) by wave 0, 4 chunks with carry
    if (t < 64) {
        int carry = 0;
        #pragma unroll
        for (int c2 = 0; c2 < 4; ++c2) {
            const int idx = c2 * 64 + t;
            const int v = histN[idx];
            int s = v;
            #pragma unroll
            for (int off = 1; off < 64; off <<= 1) {
                const int u = __shfl_up(s, off, 64);
                if (t >= off) s += u;
            }
            startN[idx] = carry + s - v;
            carry += __shfl(s, 63, 64);
        }
    }
    __syncthreads();

    // place srcs grouped by node (overwrites address table - all reads done)
    #pragma unroll
    for (int j = 0; j < 9; ++j) {
        if (nl[j] >= 0) {
            const int rk = atomicAdd(&rankN[nl[j]], 1);
            vals[startN[nl[j]] + rk] = ent[j];
        }
    }
    __syncthreads();

    // atomic-free accumulate: thread t owns node t&255, slice t>>8 (4 slices)
    {
        const int node = t & 255, sl = t >> 8;
        const float ad = adst[node];
        const int rs = startN[node], re = rs + histN[node];
        float s0 = 0.f, s1 = 0.f, sw = 0.f;
        for (int i = rs + sl; i < re; i += 4) {
            const int src = (int)vals[i];
            const float4 nd = node_data[src];
            float a = nd.z + ad;
            a = (a >= 0.f) ? a : NEG_SLOPE * a;
            const float w = __expf(a);
            s0 += w * nd.x; s1 += w * nd.y; sw += w;
        }
        part0[t] = s0; part1[t] = s1; partw[t] = sw;
    }
    __syncthreads();

    // merge 4 slices + self-loop + bias, coalesced write
    if (t < NPR) {
        const int n = r * NPR + t;
        if (n < N_NODES) {
            const float A0 = part0[t] + part0[t + 256] + part0[t + 512] + part0[t + 768];
            const float A1 = part1[t] + part1[t + 256] + part1[t + 512] + part1[t + 768];
            const float AW = partw[t] + partw[t + 256] + partw[t + 512] + partw[t + 768];
            const float4 nd = node_data[n];
            float a = nd.z + nd.w;               // self-loop logit
            a = (a >= 0.f) ? a : NEG_SLOPE * a;
            const float w = __expf(a);
            const float den = AW + w + 1e-16f;
            const float o0 = (A0 + w * nd.x) / den + bias[0];
            const float o1 = (A1 + w * nd.y) / den + bias[1];
            *reinterpret_cast<float2*>(out + (size_t)n * 2) = make_float2(o0, o1);
        }
    }
}

// ------------------- last-resort fallback (round-2 path) -------------------
__global__ __launch_bounds__(256) void proj_kernel(
    const float* __restrict__ x, const float* __restrict__ W,
    const float* __restrict__ att_src, const float* __restrict__ att_dst,
    float4* __restrict__ node_data, float4* __restrict__ accum)
{
    const int wave = (blockIdx.x * blockDim.x + threadIdx.x) >> 6;
    const int lane = threadIdx.x & 63;
    if (wave >= N_NODES) return;
    float p0 = 0.f, p1 = 0.f;
    if (lane < 48) {
        const float4 xv = *reinterpret_cast<const float4*>(x + (size_t)wave * IN_DIM + lane * 4);
        const float* Wr = W + lane * 4 * 2;
        p0 = xv.x * Wr[0] + xv.y * Wr[2] + xv.z * Wr[4] + xv.w * Wr[6];
        p1 = xv.x * Wr[1] + xv.y * Wr[3] + xv.z * Wr[5] + xv.w * Wr[7];
    }
    #pragma unroll
    for (int off = 32; off >= 1; off >>= 1) {
        p0 += __shfl_down(p0, off, 64);
        p1 += __shfl_down(p1, off, 64);
    }
    if (lane == 0) {
        const float as = p0 * att_src[0] + p1 * att_src[1];
        const float ad = p0 * att_dst[0] + p1 * att_dst[1];
        node_data[wave] = make_float4(p0, p1, as, ad);
        if (accum) accum[wave] = make_float4(0.f, 0.f, 0.f, 0.f);
    }
}

__global__ __launch_bounds__(256) void edge_kernel_atomic(
    const int* __restrict__ ei, const float4* __restrict__ node_data,
    float* __restrict__ accum)
{
    const int t = blockIdx.x * blockDim.x + threadIdx.x;
    const int base = t * 4;
    if (base >= N_EDGES) return;
    const int4 s4 = *reinterpret_cast<const int4*>(ei + base);
    const int4 d4 = *reinterpret_cast<const int4*>(ei + N_EDGES + base);
    const int ss[4] = {s4.x, s4.y, s4.z, s4.w};
    const int dd[4] = {d4.x, d4.y, d4.z, d4.w};
    #pragma unroll
    for (int k = 0; k < 4; ++k) {
        const int s = ss[k], d = dd[k];
        const float4 nds = node_data[s];
        const float ad = reinterpret_cast<const float*>(node_data)[d * 4 + 3];
        float a = nds.z + ad;
        a = (a >= 0.f) ? a : NEG_SLOPE * a;
        const float w = __expf(a);
        atomicAdd(&accum[d * 4 + 0], w * nds.x);
        atomicAdd(&accum[d * 4 + 1], w * nds.y);
        atomicAdd(&accum[d * 4 + 2], w);
    }
}

__global__ __launch_bounds__(256) void finalize_kernel(
    const float4* __restrict__ node_data, const float4* __restrict__ accum,
    const float* __restrict__ bias, float* __restrict__ out)
{
    const int n = blockIdx.x * blockDim.x + threadIdx.x;
    if (n >= N_NODES) return;
    const float4 nd = node_data[n];
    const float4 ac = accum[n];
    float a = nd.z + nd.w;
    a = (a >= 0.f) ? a : NEG_SLOPE * a;
    const float w = __expf(a);
    const float den = ac.z + w + 1e-16f;
    const float o0 = (ac.x + w * nd.x) / den + bias[0];
    const float o1 = (ac.y + w * nd.y) / den + bias[1];
    *reinterpret_cast<float2*>(out + (size_t)n * 2) = make_float2(o0, o1);
}

extern "C" void kernel_launch(void* const* d_in, const int* in_sizes, int n_in,
                              void* d_out, int out_size, void* d_ws, size_t ws_size,
                              hipStream_t stream) {
    const float* x       = (const float*)d_in[0];
    const int*   ei      = (const int*)d_in[1];
    const float* W       = (const float*)d_in[3];
    const float* att_src = (const float*)d_in[4];
    const float* att_dst = (const float*)d_in[5];
    const float* bias    = (const float*)d_in[6];
    float* out = (float*)d_out;

    char* p = (char*)d_ws;
    float4* node_data = (float4*)p;            p += (size_t)N_NODES * 16;        // 1.6 MB
    unsigned int* ipack = (unsigned int*)p;    p += (size_t)P1BLK * EPB * 4;     // 12.8 MB
    int* boundary = (int*)p;                   p += (size_t)P1BLK * BST * 4;     // 613 KB
    const size_t need = (size_t)(p - (char*)d_ws);

    if (ws_size >= need) {
        k1_proj_pass1<<<P1BLK + PROJ_BLOCKS, 1024, 0, stream>>>(
            x, W, att_src, att_dst, node_data, ei, ipack, boundary);
        k2_region_agg<<<NREG2, 1024, 0, stream>>>(ipack, boundary, node_data, bias, out);
    } else {
        float4* nd2 = (float4*)d_ws;
        float4* accum = nd2 + N_NODES;
        proj_kernel<<<(N_NODES + 3) / 4, 256, 0, stream>>>(x, W, att_src, att_dst, nd2, accum);
        edge_kernel_atomic<<<(N_EDGES / 4 + 255) / 256, 256, 0, stream>>>(ei, nd2, (float*)accum);
        finalize_kernel<<<(N_NODES + 255) / 256, 256, 0, stream>>>(nd2, accum, bias, out);
    }
}